// Round 1
// baseline (984.663 us; speedup 1.0000x reference)
//
#include <hip/hip_runtime.h>
#include <hip/hip_bf16.h>

typedef unsigned short u16;
typedef __attribute__((ext_vector_type(8))) short short8;
typedef __attribute__((ext_vector_type(4))) float f32x4;
typedef const __attribute__((address_space(1))) void GV;
typedef __attribute__((address_space(3))) void LV;
#define GLOAD16(g, l) __builtin_amdgcn_global_load_lds((GV*)(g), (LV*)(l), 16, 0, 0)

#define BATCH 512
#define LSEQ  64
#define EMB   1024
#define NH    16
#define NQKV  3200              // 1024 q | 1024 k | 1024 v | 32 sc | 96 pad
#define MROWS (BATCH*LSEQ)      // 32768

__device__ __forceinline__ u16 f2b(float f){
  __hip_bfloat16 h = __float2bfloat16(f);
  return *reinterpret_cast<u16*>(&h);
}
__device__ __forceinline__ float b2f(u16 u){
  return __uint_as_float(((unsigned)u) << 16);
}

// ---------------------------------------------------------------- conversions
__global__ __launch_bounds__(256) void f32_to_bf16_v4(const float* __restrict__ src,
                                                      u16* __restrict__ dst){
  size_t i = ((size_t)blockIdx.x * 256 + threadIdx.x) * 4;
  float4 v = *(const float4*)&src[i];
  unsigned lo = (unsigned)f2b(v.x) | ((unsigned)f2b(v.y) << 16);
  unsigned hi = (unsigned)f2b(v.z) | ((unsigned)f2b(v.w) << 16);
  *(uint2*)&dst[i] = make_uint2(lo, hi);
}

// dst[(dstRowOff+n)*dstLd + k] = bf16(src[k*N + n])   (src is [K][N] fp32)
__global__ __launch_bounds__(256) void transpose_to_bf16(const float* __restrict__ src,
                                                         u16* __restrict__ dst,
                                                         int K, int N, int dstLd, int dstRowOff){
  __shared__ float t[32][33];
  int nbx = N >> 5;
  int bx = blockIdx.x % nbx, by = blockIdx.x / nbx;
  int n0 = bx << 5, k0 = by << 5;
  int lx = threadIdx.x & 31, ly = threadIdx.x >> 5;   // 32 x 8
  #pragma unroll
  for (int i = 0; i < 32; i += 8)
    t[ly + i][lx] = src[(size_t)(k0 + ly + i) * N + n0 + lx];
  __syncthreads();
  #pragma unroll
  for (int i = 0; i < 32; i += 8)
    dst[(size_t)(dstRowOff + n0 + ly + i) * dstLd + k0 + lx] = f2b(t[lx][ly + i]);
}

__global__ __launch_bounds__(256) void build_qkv_bias(const float* __restrict__ bq,
                                                      const float* __restrict__ bk,
                                                      const float* __restrict__ bv,
                                                      float* __restrict__ out){
  int i = blockIdx.x * 256 + threadIdx.x;
  if (i < NQKV){
    float v = 0.f;
    if (i < 1024) v = bq[i];
    else if (i < 2048) v = bk[i - 1024];
    else if (i < 3072) v = bv[i - 2048];
    out[i] = v;
  }
}

// ---------------------------------------------------------------- GEMM (bf16 MFMA)
// C[M,N] = A[M,K] @ Bt[N,K]^T (+bias[N]).  128x128 tile, BK=32, 4 waves (2x2),
// double-buffered LDS fed by global_load_lds dwordx4.
template<int OUT_BF16, int HAS_BIAS>
__global__ __launch_bounds__(256) void gemm_bt(const u16* __restrict__ A,
                                               const u16* __restrict__ Bt,
                                               const float* __restrict__ bias,
                                               void* __restrict__ Cv,
                                               int M, int N, int K){
  __shared__ u16 lA[2][128 * 32];
  __shared__ u16 lB[2][128 * 32];
  const int ntn = N >> 7;
  const int tm = blockIdx.x / ntn, tn = blockIdx.x % ntn;
  const int m0 = tm << 7, n0 = tn << 7;
  const int tid = threadIdx.x;
  const int w = tid >> 6, lane = tid & 63;
  const int wm = w >> 1, wn = w & 1;

  // chunk c = i*256 + w*64 + lane  ->  row r=c>>2 of the tile, 16B piece cc=c&3
  size_t aoff[2], boff[2];
  #pragma unroll
  for (int i = 0; i < 2; i++){
    int c = i * 256 + w * 64 + lane;
    int r = c >> 2, cc = c & 3;
    aoff[i] = (size_t)(m0 + r) * K + cc * 8;
    boff[i] = (size_t)(n0 + r) * K + cc * 8;
  }

  const int nk = K >> 5;
  auto stage = [&](int buf, int kt){
    int k0 = kt << 5;
    #pragma unroll
    for (int i = 0; i < 2; i++){
      GLOAD16(A  + aoff[i] + k0, &lA[buf][(i * 256 + w * 64) * 8]);
      GLOAD16(Bt + boff[i] + k0, &lB[buf][(i * 256 + w * 64) * 8]);
    }
  };

  f32x4 acc[4][4] = {};
  stage(0, 0);
  __syncthreads();

  for (int kt = 0; kt < nk; ++kt){
    int cur = kt & 1;
    if (kt + 1 < nk) stage(cur ^ 1, kt + 1);
    const u16* la = lA[cur];
    const u16* lb = lB[cur];
    short8 af[4], bfr[4];
    #pragma unroll
    for (int f = 0; f < 4; f++){
      int ra = wm * 64 + f * 16 + (lane & 15);
      af[f]  = *(const short8*)&la[ra * 32 + (lane >> 4) * 8];
      int rb = wn * 64 + f * 16 + (lane & 15);
      bfr[f] = *(const short8*)&lb[rb * 32 + (lane >> 4) * 8];
    }
    #pragma unroll
    for (int fm = 0; fm < 4; fm++)
      #pragma unroll
      for (int fn = 0; fn < 4; fn++)
        acc[fm][fn] = __builtin_amdgcn_mfma_f32_16x16x32_bf16(af[fm], bfr[fn], acc[fm][fn], 0, 0, 0);
    __syncthreads();
  }

  #pragma unroll
  for (int fm = 0; fm < 4; fm++){
    #pragma unroll
    for (int fn = 0; fn < 4; fn++){
      int col = n0 + wn * 64 + fn * 16 + (lane & 15);
      float bv = HAS_BIAS ? bias[col] : 0.0f;
      #pragma unroll
      for (int j = 0; j < 4; j++){
        int row = m0 + wm * 64 + fm * 16 + (lane >> 4) * 4 + j;
        float v = acc[fm][fn][j] + bv;
        if (OUT_BF16) ((u16*)Cv)[(size_t)row * N + col] = f2b(v);
        else          ((float*)Cv)[(size_t)row * N + col] = v;
      }
    }
  }
}

// ---------------------------------------------------------------- smolgen hidden
// hidden[b][j] = LN256( silu(compressed[b] @ sh1_w + sh1_b) ); 2 batches/block.
__device__ __forceinline__ float2 block_sum2(float a, float b, float* s, int tid){
  #pragma unroll
  for (int o = 32; o > 0; o >>= 1){ a += __shfl_down(a, o); b += __shfl_down(b, o); }
  int w = tid >> 6, lane = tid & 63;
  __syncthreads();
  if (lane == 0){ s[w * 2] = a; s[w * 2 + 1] = b; }
  __syncthreads();
  a = s[0] + s[2] + s[4] + s[6];
  b = s[1] + s[3] + s[5] + s[7];
  return make_float2(a, b);
}

__global__ __launch_bounds__(256) void smol_hidden(const u16* __restrict__ qkvb,
                                                   const float* __restrict__ sh1_w,
                                                   const float* __restrict__ sh1_b,
                                                   const float* __restrict__ ln1_g,
                                                   const float* __restrict__ ln1_b,
                                                   float* __restrict__ hidden){
  const int b0 = blockIdx.x * 2;
  const int tid = threadIdx.x;
  __shared__ u16 cb[2][2048];
  __shared__ float rs[8];
  #pragma unroll
  for (int bi = 0; bi < 2; bi++){
    int l = tid >> 2, cc = tid & 3;   // compressed[b][l*32 + cc*8 .. +7]
    *(short8*)&cb[bi][tid * 8] =
        *(const short8*)&qkvb[(size_t)((b0 + bi) * 64 + l) * NQKV + 3072 + cc * 8];
  }
  __syncthreads();
  float acc0 = 0.f, acc1 = 0.f;
  for (int k8 = 0; k8 < 256; k8++){
    short8 c0 = *(const short8*)&cb[0][k8 * 8];
    short8 c1 = *(const short8*)&cb[1][k8 * 8];
    #pragma unroll
    for (int e = 0; e < 8; e++){
      float wv = sh1_w[(size_t)(k8 * 8 + e) * 256 + tid];
      acc0 += wv * b2f((u16)c0[e]);
      acc1 += wv * b2f((u16)c1[e]);
    }
  }
  float y0 = acc0 + sh1_b[tid]; y0 = y0 / (1.f + __expf(-y0));
  float y1 = acc1 + sh1_b[tid]; y1 = y1 / (1.f + __expf(-y1));
  float2 r0 = block_sum2(y0, y0 * y0, rs, tid);
  float2 r1 = block_sum2(y1, y1 * y1, rs, tid);
  float m0 = r0.x * (1.f / 256.f), v0 = r0.y * (1.f / 256.f) - m0 * m0;
  float m1 = r1.x * (1.f / 256.f), v1 = r1.y * (1.f / 256.f) - m1 * m1;
  hidden[(size_t)(b0    ) * 256 + tid] = (y0 - m0) * rsqrtf(v0 + 1e-3f) * ln1_g[tid] + ln1_b[tid];
  hidden[(size_t)(b0 + 1) * 256 + tid] = (y1 - m1) * rsqrtf(v1 + 1e-3f) * ln1_g[tid] + ln1_b[tid];
}

// ---------------------------------------------------------------- smolgen gen
// gen[b][:4096] = LN4096( silu(hidden[b] @ sg_w + sg_b) ) -> bf16; 2 batches/block.
__global__ __launch_bounds__(256) void smol_gen(const float* __restrict__ hidden,
                                                const float* __restrict__ sg_w,
                                                const float* __restrict__ sg_b,
                                                const float* __restrict__ ln2_g,
                                                const float* __restrict__ ln2_b,
                                                u16* __restrict__ genb){
  const int b0 = blockIdx.x * 2;
  const int tid = threadIdx.x;
  __shared__ float hb[2][256];
  __shared__ float rs[8];
  hb[0][tid] = hidden[(size_t)b0 * 256 + tid];
  hb[1][tid] = hidden[(size_t)(b0 + 1) * 256 + tid];
  __syncthreads();
  float a0[16] = {}, a1[16] = {};
  for (int k = 0; k < 256; k++){
    float h0 = hb[0][k], h1 = hb[1][k];
    #pragma unroll
    for (int ci = 0; ci < 16; ci++){
      float wv = sg_w[(size_t)k * 4096 + ci * 256 + tid];
      a0[ci] += h0 * wv;
      a1[ci] += h1 * wv;
    }
  }
  float s0 = 0, q0 = 0, s1 = 0, q1 = 0;
  #pragma unroll
  for (int ci = 0; ci < 16; ci++){
    int col = ci * 256 + tid;
    float y = a0[ci] + sg_b[col]; y = y / (1.f + __expf(-y)); a0[ci] = y; s0 += y; q0 += y * y;
    y = a1[ci] + sg_b[col];       y = y / (1.f + __expf(-y)); a1[ci] = y; s1 += y; q1 += y * y;
  }
  float2 r0 = block_sum2(s0, q0, rs, tid);
  float2 r1 = block_sum2(s1, q1, rs, tid);
  float m0 = r0.x * (1.f / 4096.f), v0 = r0.y * (1.f / 4096.f) - m0 * m0;
  float m1 = r1.x * (1.f / 4096.f), v1 = r1.y * (1.f / 4096.f) - m1 * m1;
  float is0 = rsqrtf(v0 + 1e-3f), is1 = rsqrtf(v1 + 1e-3f);
  #pragma unroll
  for (int ci = 0; ci < 16; ci++){
    int col = ci * 256 + tid;
    genb[(size_t)(b0    ) * 4096 + col] = f2b((a0[ci] - m0) * is0 * ln2_g[col] + ln2_b[col]);
    genb[(size_t)(b0 + 1) * 4096 + col] = f2b((a1[ci] - m1) * is1 * ln2_g[col] + ln2_b[col]);
  }
}

// ---------------------------------------------------------------- fused attention
// one block per (b,h): S = QK^T/8 + smol; softmax; O = P V; bf16 out [32768,1024]
__global__ __launch_bounds__(256) void attn_fused(const u16* __restrict__ qkvb,
                                                  const float* __restrict__ smol,
                                                  u16* __restrict__ aout){
  const int bh = blockIdx.x;
  const int b = bh >> 4, h = bh & 15;
  __shared__ u16 qs[4096], kts[4096], vts[4096], ps[4096];
  __shared__ float Ss[64 * 68];
  const int tid = threadIdx.x, w = tid >> 6, lane = tid & 63;
  const int wm = w >> 1, wn = w & 1;

  const u16* qb = qkvb + (size_t)(b * 64) * NQKV + h * 64;
  const u16* kb = qb + 1024;
  const u16* vb = qb + 2048;

  // stage q,k (row-major [pos][hd], 8 x 16B chunks/row, chunk XOR-swizzled) and v^T
  #pragma unroll
  for (int i = 0; i < 2; i++){
    int c = i * 256 + tid;
    int r = c >> 3, cc = c & 7;
    int pc = cc ^ (r & 7);
    *(short8*)&qs [r * 64 + pc * 8] = *(const short8*)&qb[(size_t)r * NQKV + cc * 8];
    *(short8*)&kts[r * 64 + pc * 8] = *(const short8*)&kb[(size_t)r * NQKV + cc * 8];
    short8 vv = *(const short8*)&vb[(size_t)r * NQKV + cc * 8];
    #pragma unroll
    for (int j = 0; j < 8; j++){
      int hd = cc * 8 + j;                 // vT row = hd, col = r (kpos)
      int pcv = (r >> 3) ^ (hd & 7);
      vts[hd * 64 + pcv * 8 + (r & 7)] = (u16)vv[j];
    }
  }
  __syncthreads();

  // QK^T: each wave 32x32 (2x2 frags), K = 64 -> 2 mfma steps
  f32x4 sacc[2][2] = {};
  #pragma unroll
  for (int ksi = 0; ksi < 2; ksi++){
    short8 af[2], bfr[2];
    #pragma unroll
    for (int f = 0; f < 2; f++){
      int ra = wm * 32 + f * 16 + (lane & 15);
      int ca = ksi * 4 + (lane >> 4);
      af[f]  = *(const short8*)&qs [ra * 64 + (ca ^ (ra & 7)) * 8];
      int rb = wn * 32 + f * 16 + (lane & 15);
      bfr[f] = *(const short8*)&kts[rb * 64 + (ca ^ (rb & 7)) * 8];
    }
    #pragma unroll
    for (int fm = 0; fm < 2; fm++)
      #pragma unroll
      for (int fn = 0; fn < 2; fn++)
        sacc[fm][fn] = __builtin_amdgcn_mfma_f32_16x16x32_bf16(af[fm], bfr[fn], sacc[fm][fn], 0, 0, 0);
  }
  const float* sm = smol + (size_t)bh * 4096;
  #pragma unroll
  for (int fm = 0; fm < 2; fm++)
    #pragma unroll
    for (int fn = 0; fn < 2; fn++)
      #pragma unroll
      for (int j = 0; j < 4; j++){
        int q  = wm * 32 + fm * 16 + (lane >> 4) * 4 + j;
        int kp = wn * 32 + fn * 16 + (lane & 15);
        Ss[q * 68 + kp] = sacc[fm][fn][j] * 0.125f + sm[q * 64 + kp];
      }
  __syncthreads();

  // softmax: 4 lanes per row, each lane 16 contiguous cols
  {
    int row = w * 16 + (lane >> 2);
    int sub = lane & 3;
    float* srow = &Ss[row * 68];
    float vals[16];
    float mx = -3.4e38f;
    #pragma unroll
    for (int i = 0; i < 16; i++){ vals[i] = srow[sub * 16 + i]; mx = fmaxf(mx, vals[i]); }
    mx = fmaxf(mx, __shfl_xor(mx, 1));
    mx = fmaxf(mx, __shfl_xor(mx, 2));
    float s = 0.f;
    #pragma unroll
    for (int i = 0; i < 16; i++){ vals[i] = __expf(vals[i] - mx); s += vals[i]; }
    s += __shfl_xor(s, 1);
    s += __shfl_xor(s, 2);
    float rinv = 1.f / s;
    short8 o0, o1;
    #pragma unroll
    for (int i = 0; i < 8; i++){ o0[i] = (short)f2b(vals[i] * rinv); o1[i] = (short)f2b(vals[8 + i] * rinv); }
    int c0 = sub * 2, c1 = sub * 2 + 1;
    *(short8*)&ps[row * 64 + (c0 ^ (row & 7)) * 8] = o0;
    *(short8*)&ps[row * 64 + (c1 ^ (row & 7)) * 8] = o1;
  }
  __syncthreads();

  // O = P @ V   (A = P rows, B^T = vT rows)
  f32x4 oacc[2][2] = {};
  #pragma unroll
  for (int ksi = 0; ksi < 2; ksi++){
    short8 af[2], bfr[2];
    #pragma unroll
    for (int f = 0; f < 2; f++){
      int ra = wm * 32 + f * 16 + (lane & 15);
      int ca = ksi * 4 + (lane >> 4);
      af[f]  = *(const short8*)&ps [ra * 64 + (ca ^ (ra & 7)) * 8];
      int rb = wn * 32 + f * 16 + (lane & 15);
      bfr[f] = *(const short8*)&vts[rb * 64 + (ca ^ (rb & 7)) * 8];
    }
    #pragma unroll
    for (int fm = 0; fm < 2; fm++)
      #pragma unroll
      for (int fn = 0; fn < 2; fn++)
        oacc[fm][fn] = __builtin_amdgcn_mfma_f32_16x16x32_bf16(af[fm], bfr[fn], oacc[fm][fn], 0, 0, 0);
  }
  #pragma unroll
  for (int fm = 0; fm < 2; fm++)
    #pragma unroll
    for (int fn = 0; fn < 2; fn++)
      #pragma unroll
      for (int j = 0; j < 4; j++){
        int q  = wm * 32 + fm * 16 + (lane >> 4) * 4 + j;
        int hd = wn * 32 + fn * 16 + (lane & 15);
        aout[(size_t)(b * 64 + q) * 1024 + h * 64 + hd] = f2b(oacc[fm][fn][j]);
      }
}

// ---------------------------------------------------------------- launcher
extern "C" void kernel_launch(void* const* d_in, const int* in_sizes, int n_in,
                              void* d_out, int out_size, void* d_ws, size_t ws_size,
                              hipStream_t stream){
  const float* x     = (const float*)d_in[0];
  const float* wq    = (const float*)d_in[1];
  const float* bq    = (const float*)d_in[2];
  const float* wk    = (const float*)d_in[3];
  const float* bk    = (const float*)d_in[4];
  const float* wv    = (const float*)d_in[5];
  const float* bv    = (const float*)d_in[6];
  const float* wo    = (const float*)d_in[7];
  const float* bo    = (const float*)d_in[8];
  const float* sc_w  = (const float*)d_in[9];
  const float* sh1_w = (const float*)d_in[10];
  const float* sh1_b = (const float*)d_in[11];
  const float* ln1_g = (const float*)d_in[12];
  const float* ln1_b = (const float*)d_in[13];
  const float* sg_w  = (const float*)d_in[14];
  const float* sg_b  = (const float*)d_in[15];
  const float* ln2_g = (const float*)d_in[16];
  const float* ln2_b = (const float*)d_in[17];
  const float* swg_w = (const float*)d_in[18];

  char* ws = (char*)d_ws;
  size_t off = 0;
  auto alloc = [&](size_t bytes){ void* p = ws + off; off += (bytes + 255) & ~(size_t)255; return p; };
  u16*   xb    = (u16*)  alloc((size_t)MROWS * EMB * 2);     // x in bf16
  u16*   wqkvT = (u16*)  alloc((size_t)NQKV * EMB * 2);      // [3200][1024]
  float* qbias = (float*)alloc((size_t)NQKV * 4);
  u16*   woT   = (u16*)  alloc((size_t)1024 * 1024 * 2);
  u16*   swgT  = (u16*)  alloc((size_t)4096 * 256 * 2);
  u16*   qkvb  = (u16*)  alloc((size_t)MROWS * NQKV * 2);    // q|k|v|compressed bf16
  float* hid   = (float*)alloc((size_t)512 * 256 * 4);
  u16*   genb  = (u16*)  alloc((size_t)512 * 4096 * 2);      // = [8192][256] bf16
  float* smol  = (float*)alloc((size_t)8192 * 4096 * 4);     // [b*16+h][q*64+k]
  u16*   aout  = (u16*)  alloc((size_t)MROWS * 1024 * 2);    // attn output bf16

  // --- conversions / transposes (bf16, B^T layout) ---
  f32_to_bf16_v4<<<(MROWS * EMB) / 1024, 256, 0, stream>>>(x, xb);
  transpose_to_bf16<<<1024, 256, 0, stream>>>(wq,   wqkvT, 1024, 1024, 1024, 0);
  transpose_to_bf16<<<1024, 256, 0, stream>>>(wk,   wqkvT, 1024, 1024, 1024, 1024);
  transpose_to_bf16<<<1024, 256, 0, stream>>>(wv,   wqkvT, 1024, 1024, 1024, 2048);
  transpose_to_bf16<<<32,   256, 0, stream>>>(sc_w, wqkvT, 1024, 32,   1024, 3072);
  hipMemsetAsync(wqkvT + (size_t)3104 * 1024, 0, (size_t)96 * 1024 * 2, stream);  // pad rows
  transpose_to_bf16<<<1024, 256, 0, stream>>>(wo,    woT,  1024, 1024, 1024, 0);
  transpose_to_bf16<<<1024, 256, 0, stream>>>(swg_w, swgT, 256,  4096, 256,  0);
  build_qkv_bias<<<13, 256, 0, stream>>>(bq, bk, bv, qbias);

  // --- fused QKV + compressed projection: [32768,1024] @ [1024,3200] ---
  gemm_bt<1, 1><<<(MROWS / 128) * (NQKV / 128), 256, 0, stream>>>(
      xb, wqkvT, qbias, qkvb, MROWS, NQKV, 1024);

  // --- smolgen chain ---
  smol_hidden<<<BATCH / 2, 256, 0, stream>>>(qkvb, sh1_w, sh1_b, ln1_g, ln1_b, hid);
  smol_gen   <<<BATCH / 2, 256, 0, stream>>>(hid, sg_w, sg_b, ln2_g, ln2_b, genb);
  gemm_bt<0, 0><<<(8192 / 128) * (4096 / 128), 256, 0, stream>>>(
      genb, swgT, nullptr, smol, 8192, 4096, 256);

  // --- attention ---
  attn_fused<<<BATCH * NH, 256, 0, stream>>>(qkvb, smol, aout);

  // --- output projection: [32768,1024] @ [1024,1024] + bo -> fp32 d_out ---
  gemm_bt<0, 1><<<(MROWS / 128) * (1024 / 128), 256, 0, stream>>>(
      aout, woT, bo, d_out, MROWS, 1024, 1024);
}

// Round 2
// 942.946 us; speedup vs baseline: 1.0442x; 1.0442x over previous
//
#include <hip/hip_runtime.h>
#include <hip/hip_bf16.h>

typedef unsigned short u16;
typedef __attribute__((ext_vector_type(8))) short short8;
typedef __attribute__((ext_vector_type(4))) float f32x4;
typedef const __attribute__((address_space(1))) void GV;
typedef __attribute__((address_space(3))) void LV;
#define GLOAD16(g, l) __builtin_amdgcn_global_load_lds((GV*)(g), (LV*)(l), 16, 0, 0)
#define BAR() asm volatile("s_barrier" ::: "memory")

#define BATCH 512
#define LSEQ  64
#define EMB   1024
#define NH    16
#define NQKV  3328              // 1024 q | 1024 k | 1024 v | 32 sc | 224 pad (multiple of 256)
#define MROWS (BATCH*LSEQ)      // 32768

__device__ __forceinline__ u16 f2b(float f){
  __hip_bfloat16 h = __float2bfloat16(f);
  return *reinterpret_cast<u16*>(&h);
}
__device__ __forceinline__ float b2f(u16 u){
  return __uint_as_float(((unsigned)u) << 16);
}

// ---------------------------------------------------------------- conversions
__global__ __launch_bounds__(256) void f32_to_bf16_v4(const float* __restrict__ src,
                                                      u16* __restrict__ dst){
  size_t i = ((size_t)blockIdx.x * 256 + threadIdx.x) * 4;
  float4 v = *(const float4*)&src[i];
  unsigned lo = (unsigned)f2b(v.x) | ((unsigned)f2b(v.y) << 16);
  unsigned hi = (unsigned)f2b(v.z) | ((unsigned)f2b(v.w) << 16);
  *(uint2*)&dst[i] = make_uint2(lo, hi);
}

// dst[(dstRowOff+n)*dstLd + k] = bf16(src[k*N + n])   (src is [K][N] fp32)
__global__ __launch_bounds__(256) void transpose_to_bf16(const float* __restrict__ src,
                                                         u16* __restrict__ dst,
                                                         int K, int N, int dstLd, int dstRowOff){
  __shared__ float t[32][33];
  int nbx = N >> 5;
  int bx = blockIdx.x % nbx, by = blockIdx.x / nbx;
  int n0 = bx << 5, k0 = by << 5;
  int lx = threadIdx.x & 31, ly = threadIdx.x >> 5;   // 32 x 8
  #pragma unroll
  for (int i = 0; i < 32; i += 8)
    t[ly + i][lx] = src[(size_t)(k0 + ly + i) * N + n0 + lx];
  __syncthreads();
  #pragma unroll
  for (int i = 0; i < 32; i += 8)
    dst[(size_t)(dstRowOff + n0 + ly + i) * dstLd + k0 + lx] = f2b(t[lx][ly + i]);
}

__global__ __launch_bounds__(256) void build_qkv_bias(const float* __restrict__ bq,
                                                      const float* __restrict__ bk,
                                                      const float* __restrict__ bv,
                                                      float* __restrict__ out){
  int i = blockIdx.x * 256 + threadIdx.x;
  if (i < NQKV){
    float v = 0.f;
    if (i < 1024) v = bq[i];
    else if (i < 2048) v = bk[i - 1024];
    else if (i < 3072) v = bv[i - 2048];
    out[i] = v;
  }
}

// ---------------------------------------------------------------- 256x256 8-phase GEMM
// C[M,N] = A[M,K] @ Bt[N,K]^T (+bias[N]).  BM=BN=256, BK=64, 8 waves (2Mx4N,
// interleaved), 128 KiB LDS double-buffer, T2 XOR-swizzle, counted vmcnt(6),
// setprio around MFMA clusters, bijective XCD blockIdx swizzle.
//
// Wave tiling (interleaved so each phase quadrant touches ONE A-half/B-half
// uniformly across waves):  A row-frag f (0..7): row = f*32 + wm*16 + (lane&15)
//                           B col-frag g (0..3): col = g*64 + wn*16 + (lane&15)
// Phases per K-tile t: p1 (A0xB0, ds A0+B0, stage A1(t+1)); p2 (A0xB1, ds B1,
// stage A0(t+2)); p3 (A1xB1, ds A1, stage B0(t+2)); p4 (A1xB0, stage B1(t+2),
// vmcnt(6) boundary wait -> confirms ALL of tile t+1, leaves 3 half-tiles in
// flight).  Each overwritten LDS half-region is dead after its ds phase.
template<int OUT_BF16, int HAS_BIAS>
__global__ __launch_bounds__(512, 2) void gemm256(const u16* __restrict__ A,
                                                  const u16* __restrict__ Bt,
                                                  const float* __restrict__ bias,
                                                  void* __restrict__ Cv,
                                                  int M, int N, int K){
  __shared__ u16 lA[2][16384];   // [buf][half*8192 + row*64 + swz_slot*8]
  __shared__ u16 lB[2][16384];
  const int ntn = N >> 8;
  // bijective XCD swizzle (m204)
  const int nwg = gridDim.x, bid = blockIdx.x;
  const int qq = nwg >> 3, r8 = nwg & 7, xcd = bid & 7, kk = bid >> 3;
  const int wg = (xcd < r8 ? xcd * (qq + 1) : r8 * (qq + 1) + (xcd - r8) * qq) + kk;
  const int tm = wg / ntn, tn = wg % ntn;
  const int m0 = tm << 8, n0 = tn << 8;
  const int tid = threadIdx.x;
  const int w = tid >> 6, lane = tid & 63;
  const int wm = w >> 2, wn = w & 3;
  const int l15 = lane & 15, l4 = lane >> 4;

  // staging: half-tile = 128 rows x 64 cols bf16 = 1024 x 16B chunks; wave w
  // owns chunks [w*128, w*128+128) via 2 GLOAD16. LDS dest linear (wave-uniform
  // base + lane*16); global source pre-swizzled: chunk at linear (rh, s) holds
  // global k-chunk (s ^ (rh&7)).
  size_t ga[2][2], gb[2][2];
  #pragma unroll
  for (int j = 0; j < 2; j++){
    int ci = w * 128 + j * 64 + lane;
    int rh = ci >> 3, s = ci & 7;
    int gk = (s ^ (rh & 7)) * 8;
    #pragma unroll
    for (int h = 0; h < 2; h++){
      ga[h][j] = (size_t)(m0 + h * 128 + rh) * K + gk;
      gb[h][j] = (size_t)(n0 + h * 128 + rh) * K + gk;
    }
  }
  const int nk = K >> 6;

  auto stA = [&](int buf, int h, int kt){
    #pragma unroll
    for (int j = 0; j < 2; j++)
      GLOAD16(A + ga[h][j] + (size_t)kt * 64, &lA[buf][h * 8192 + (w * 128 + j * 64) * 8]);
  };
  auto stB = [&](int buf, int h, int kt){
    #pragma unroll
    for (int j = 0; j < 2; j++)
      GLOAD16(Bt + gb[h][j] + (size_t)kt * 64, &lB[buf][h * 8192 + (w * 128 + j * 64) * 8]);
  };

  // prologue: tile0 {A0,B0,B1,A1}, tile1 {A0,B0,B1} -> 14 loads; vmcnt(6)
  // confirms ALL of tile0, leaves tile1's {A0,B0,B1} in flight.
  stA(0, 0, 0); stB(0, 0, 0); stB(0, 1, 0); stA(0, 1, 0);
  stA(1, 0, 1); stB(1, 0, 1); stB(1, 1, 1);
  asm volatile("s_waitcnt vmcnt(6)" ::: "memory");
  BAR();

  f32x4 acc[8][4] = {};
  short8 a[4][2], b[4][2];

  for (int t = 0; t < nk; ++t){
    const int cur = t & 1;
    const u16* la = lA[cur];
    const u16* lb = lB[cur];

    // ---------------- phase 1: ds A0-frags(8) + B0-frags(4); stage A1(t+1)
    #pragma unroll
    for (int f = 0; f < 4; f++){
      int r = f * 32 + wm * 16 + l15;          // 0..127 (half 0)
      #pragma unroll
      for (int ks = 0; ks < 2; ks++){
        int c = ks * 4 + l4;
        a[f][ks] = *(const short8*)&la[r * 64 + ((c ^ (r & 7)) * 8)];
      }
    }
    #pragma unroll
    for (int g = 0; g < 2; g++){
      int r = g * 64 + wn * 16 + l15;          // 0..127 (half 0)
      #pragma unroll
      for (int ks = 0; ks < 2; ks++){
        int c = ks * 4 + l4;
        b[g][ks] = *(const short8*)&lb[r * 64 + ((c ^ (r & 7)) * 8)];
      }
    }
    if (t + 1 < nk) stA(cur ^ 1, 1, t + 1);
    BAR();
    __builtin_amdgcn_s_setprio(1);
    #pragma unroll
    for (int f = 0; f < 4; f++)
      #pragma unroll
      for (int g = 0; g < 2; g++)
        #pragma unroll
        for (int ks = 0; ks < 2; ks++)
          acc[f][g] = __builtin_amdgcn_mfma_f32_16x16x32_bf16(a[f][ks], b[g][ks], acc[f][g], 0, 0, 0);
    __builtin_amdgcn_s_setprio(0);
    BAR();

    // ---------------- phase 2: ds B1-frags(4); stage A0(t+2)
    #pragma unroll
    for (int g = 2; g < 4; g++){
      int r = g * 64 + wn * 16 + l15;          // 128..255 (half 1)
      int rh = r & 127;
      #pragma unroll
      for (int ks = 0; ks < 2; ks++){
        int c = ks * 4 + l4;
        b[g][ks] = *(const short8*)&lb[8192 + rh * 64 + ((c ^ (rh & 7)) * 8)];
      }
    }
    if (t + 2 < nk) stA(cur, 0, t + 2);
    BAR();
    __builtin_amdgcn_s_setprio(1);
    #pragma unroll
    for (int f = 0; f < 4; f++)
      #pragma unroll
      for (int g = 2; g < 4; g++)
        #pragma unroll
        for (int ks = 0; ks < 2; ks++)
          acc[f][g] = __builtin_amdgcn_mfma_f32_16x16x32_bf16(a[f][ks], b[g][ks], acc[f][g], 0, 0, 0);
    __builtin_amdgcn_s_setprio(0);
    BAR();

    // ---------------- phase 3: ds A1-frags(8); stage B0(t+2)
    #pragma unroll
    for (int f = 0; f < 4; f++){
      int r = (f + 4) * 32 + wm * 16 + l15;    // 128..255 (half 1)
      int rh = r & 127;
      #pragma unroll
      for (int ks = 0; ks < 2; ks++){
        int c = ks * 4 + l4;
        a[f][ks] = *(const short8*)&la[8192 + rh * 64 + ((c ^ (rh & 7)) * 8)];
      }
    }
    if (t + 2 < nk) stB(cur, 0, t + 2);
    BAR();
    __builtin_amdgcn_s_setprio(1);
    #pragma unroll
    for (int f = 0; f < 4; f++)
      #pragma unroll
      for (int g = 2; g < 4; g++)
        #pragma unroll
        for (int ks = 0; ks < 2; ks++)
          acc[f + 4][g] = __builtin_amdgcn_mfma_f32_16x16x32_bf16(a[f][ks], b[g][ks], acc[f + 4][g], 0, 0, 0);
    __builtin_amdgcn_s_setprio(0);
    BAR();

    // ---------------- phase 4: stage B1(t+2); boundary wait; MFMA A1xB0
    if (t + 2 < nk) stB(cur, 1, t + 2);
    if (t + 1 < nk){
      if (t + 2 < nk) asm volatile("s_waitcnt vmcnt(6)" ::: "memory");
      else            asm volatile("s_waitcnt vmcnt(0)" ::: "memory");
    }
    BAR();
    __builtin_amdgcn_s_setprio(1);
    #pragma unroll
    for (int f = 0; f < 4; f++)
      #pragma unroll
      for (int g = 0; g < 2; g++)
        #pragma unroll
        for (int ks = 0; ks < 2; ks++)
          acc[f + 4][g] = __builtin_amdgcn_mfma_f32_16x16x32_bf16(a[f][ks], b[g][ks], acc[f + 4][g], 0, 0, 0);
    __builtin_amdgcn_s_setprio(0);
    BAR();
  }

  // epilogue
  #pragma unroll
  for (int f = 0; f < 8; f++){
    #pragma unroll
    for (int g = 0; g < 4; g++){
      int col = n0 + g * 64 + wn * 16 + l15;
      float bv = HAS_BIAS ? bias[col] : 0.0f;
      #pragma unroll
      for (int j = 0; j < 4; j++){
        int row = m0 + f * 32 + wm * 16 + l4 * 4 + j;
        float v = acc[f][g][j] + bv;
        if (OUT_BF16) ((u16*)Cv)[(size_t)row * N + col] = f2b(v);
        else          ((float*)Cv)[(size_t)row * N + col] = v;
      }
    }
  }
}

// ---------------------------------------------------------------- smolgen hidden
__device__ __forceinline__ float2 block_sum2(float a, float b, float* s, int tid){
  #pragma unroll
  for (int o = 32; o > 0; o >>= 1){ a += __shfl_down(a, o); b += __shfl_down(b, o); }
  int w = tid >> 6, lane = tid & 63;
  __syncthreads();
  if (lane == 0){ s[w * 2] = a; s[w * 2 + 1] = b; }
  __syncthreads();
  a = s[0] + s[2] + s[4] + s[6];
  b = s[1] + s[3] + s[5] + s[7];
  return make_float2(a, b);
}

__global__ __launch_bounds__(256) void smol_hidden(const u16* __restrict__ qkvb,
                                                   const float* __restrict__ sh1_w,
                                                   const float* __restrict__ sh1_b,
                                                   const float* __restrict__ ln1_g,
                                                   const float* __restrict__ ln1_b,
                                                   float* __restrict__ hidden){
  const int b0 = blockIdx.x * 2;
  const int tid = threadIdx.x;
  __shared__ u16 cb[2][2048];
  __shared__ float rs[8];
  #pragma unroll
  for (int bi = 0; bi < 2; bi++){
    int l = tid >> 2, cc = tid & 3;
    *(short8*)&cb[bi][tid * 8] =
        *(const short8*)&qkvb[(size_t)((b0 + bi) * 64 + l) * NQKV + 3072 + cc * 8];
  }
  __syncthreads();
  float acc0 = 0.f, acc1 = 0.f;
  for (int k8 = 0; k8 < 256; k8++){
    short8 c0 = *(const short8*)&cb[0][k8 * 8];
    short8 c1 = *(const short8*)&cb[1][k8 * 8];
    #pragma unroll
    for (int e = 0; e < 8; e++){
      float wv = sh1_w[(size_t)(k8 * 8 + e) * 256 + tid];
      acc0 += wv * b2f((u16)c0[e]);
      acc1 += wv * b2f((u16)c1[e]);
    }
  }
  float y0 = acc0 + sh1_b[tid]; y0 = y0 / (1.f + __expf(-y0));
  float y1 = acc1 + sh1_b[tid]; y1 = y1 / (1.f + __expf(-y1));
  float2 r0 = block_sum2(y0, y0 * y0, rs, tid);
  float2 r1 = block_sum2(y1, y1 * y1, rs, tid);
  float m0 = r0.x * (1.f / 256.f), v0 = r0.y * (1.f / 256.f) - m0 * m0;
  float m1 = r1.x * (1.f / 256.f), v1 = r1.y * (1.f / 256.f) - m1 * m1;
  hidden[(size_t)(b0    ) * 256 + tid] = (y0 - m0) * rsqrtf(v0 + 1e-3f) * ln1_g[tid] + ln1_b[tid];
  hidden[(size_t)(b0 + 1) * 256 + tid] = (y1 - m1) * rsqrtf(v1 + 1e-3f) * ln1_g[tid] + ln1_b[tid];
}

// ---------------------------------------------------------------- smolgen gen
__global__ __launch_bounds__(256) void smol_gen(const float* __restrict__ hidden,
                                                const float* __restrict__ sg_w,
                                                const float* __restrict__ sg_b,
                                                const float* __restrict__ ln2_g,
                                                const float* __restrict__ ln2_b,
                                                u16* __restrict__ genb){
  const int b0 = blockIdx.x * 2;
  const int tid = threadIdx.x;
  __shared__ float hb[2][256];
  __shared__ float rs[8];
  hb[0][tid] = hidden[(size_t)b0 * 256 + tid];
  hb[1][tid] = hidden[(size_t)(b0 + 1) * 256 + tid];
  __syncthreads();
  float a0[16] = {}, a1[16] = {};
  for (int k = 0; k < 256; k++){
    float h0 = hb[0][k], h1 = hb[1][k];
    #pragma unroll
    for (int ci = 0; ci < 16; ci++){
      float wv = sg_w[(size_t)k * 4096 + ci * 256 + tid];
      a0[ci] += h0 * wv;
      a1[ci] += h1 * wv;
    }
  }
  float s0 = 0, q0 = 0, s1 = 0, q1 = 0;
  #pragma unroll
  for (int ci = 0; ci < 16; ci++){
    int col = ci * 256 + tid;
    float y = a0[ci] + sg_b[col]; y = y / (1.f + __expf(-y)); a0[ci] = y; s0 += y; q0 += y * y;
    y = a1[ci] + sg_b[col];       y = y / (1.f + __expf(-y)); a1[ci] = y; s1 += y; q1 += y * y;
  }
  float2 r0 = block_sum2(s0, q0, rs, tid);
  float2 r1 = block_sum2(s1, q1, rs, tid);
  float m0 = r0.x * (1.f / 4096.f), v0 = r0.y * (1.f / 4096.f) - m0 * m0;
  float m1 = r1.x * (1.f / 4096.f), v1 = r1.y * (1.f / 4096.f) - m1 * m1;
  float is0 = rsqrtf(v0 + 1e-3f), is1 = rsqrtf(v1 + 1e-3f);
  #pragma unroll
  for (int ci = 0; ci < 16; ci++){
    int col = ci * 256 + tid;
    genb[(size_t)(b0    ) * 4096 + col] = f2b((a0[ci] - m0) * is0 * ln2_g[col] + ln2_b[col]);
    genb[(size_t)(b0 + 1) * 4096 + col] = f2b((a1[ci] - m1) * is1 * ln2_g[col] + ln2_b[col]);
  }
}

// ---------------------------------------------------------------- fused attention
__global__ __launch_bounds__(256) void attn_fused(const u16* __restrict__ qkvb,
                                                  const float* __restrict__ smol,
                                                  u16* __restrict__ aout){
  const int bh = blockIdx.x;
  const int b = bh >> 4, h = bh & 15;
  __shared__ u16 qs[4096], kts[4096], vts[4096], ps[4096];
  __shared__ float Ss[64 * 68];
  const int tid = threadIdx.x, w = tid >> 6, lane = tid & 63;
  const int wm = w >> 1, wn = w & 1;

  const u16* qb = qkvb + (size_t)(b * 64) * NQKV + h * 64;
  const u16* kb = qb + 1024;
  const u16* vb = qb + 2048;

  #pragma unroll
  for (int i = 0; i < 2; i++){
    int c = i * 256 + tid;
    int r = c >> 3, cc = c & 7;
    int pc = cc ^ (r & 7);
    *(short8*)&qs [r * 64 + pc * 8] = *(const short8*)&qb[(size_t)r * NQKV + cc * 8];
    *(short8*)&kts[r * 64 + pc * 8] = *(const short8*)&kb[(size_t)r * NQKV + cc * 8];
    short8 vv = *(const short8*)&vb[(size_t)r * NQKV + cc * 8];
    #pragma unroll
    for (int j = 0; j < 8; j++){
      int hd = cc * 8 + j;
      int pcv = (r >> 3) ^ (hd & 7);
      vts[hd * 64 + pcv * 8 + (r & 7)] = (u16)vv[j];
    }
  }
  __syncthreads();

  f32x4 sacc[2][2] = {};
  #pragma unroll
  for (int ksi = 0; ksi < 2; ksi++){
    short8 af[2], bfr[2];
    #pragma unroll
    for (int f = 0; f < 2; f++){
      int ra = wm * 32 + f * 16 + (lane & 15);
      int ca = ksi * 4 + (lane >> 4);
      af[f]  = *(const short8*)&qs [ra * 64 + (ca ^ (ra & 7)) * 8];
      int rb = wn * 32 + f * 16 + (lane & 15);
      bfr[f] = *(const short8*)&kts[rb * 64 + (ca ^ (rb & 7)) * 8];
    }
    #pragma unroll
    for (int fm = 0; fm < 2; fm++)
      #pragma unroll
      for (int fn = 0; fn < 2; fn++)
        sacc[fm][fn] = __builtin_amdgcn_mfma_f32_16x16x32_bf16(af[fm], bfr[fn], sacc[fm][fn], 0, 0, 0);
  }
  const float* sm = smol + (size_t)bh * 4096;
  #pragma unroll
  for (int fm = 0; fm < 2; fm++)
    #pragma unroll
    for (int fn = 0; fn < 2; fn++)
      #pragma unroll
      for (int j = 0; j < 4; j++){
        int q  = wm * 32 + fm * 16 + (lane >> 4) * 4 + j;
        int kp = wn * 32 + fn * 16 + (lane & 15);
        Ss[q * 68 + kp] = sacc[fm][fn][j] * 0.125f + sm[q * 64 + kp];
      }
  __syncthreads();

  {
    int row = w * 16 + (lane >> 2);
    int sub = lane & 3;
    float* srow = &Ss[row * 68];
    float vals[16];
    float mx = -3.4e38f;
    #pragma unroll
    for (int i = 0; i < 16; i++){ vals[i] = srow[sub * 16 + i]; mx = fmaxf(mx, vals[i]); }
    mx = fmaxf(mx, __shfl_xor(mx, 1));
    mx = fmaxf(mx, __shfl_xor(mx, 2));
    float s = 0.f;
    #pragma unroll
    for (int i = 0; i < 16; i++){ vals[i] = __expf(vals[i] - mx); s += vals[i]; }
    s += __shfl_xor(s, 1);
    s += __shfl_xor(s, 2);
    float rinv = 1.f / s;
    short8 o0, o1;
    #pragma unroll
    for (int i = 0; i < 8; i++){ o0[i] = (short)f2b(vals[i] * rinv); o1[i] = (short)f2b(vals[8 + i] * rinv); }
    int c0 = sub * 2, c1 = sub * 2 + 1;
    *(short8*)&ps[row * 64 + (c0 ^ (row & 7)) * 8] = o0;
    *(short8*)&ps[row * 64 + (c1 ^ (row & 7)) * 8] = o1;
  }
  __syncthreads();

  f32x4 oacc[2][2] = {};
  #pragma unroll
  for (int ksi = 0; ksi < 2; ksi++){
    short8 af[2], bfr[2];
    #pragma unroll
    for (int f = 0; f < 2; f++){
      int ra = wm * 32 + f * 16 + (lane & 15);
      int ca = ksi * 4 + (lane >> 4);
      af[f]  = *(const short8*)&ps [ra * 64 + (ca ^ (ra & 7)) * 8];
      int rb = wn * 32 + f * 16 + (lane & 15);
      bfr[f] = *(const short8*)&vts[rb * 64 + (ca ^ (rb & 7)) * 8];
    }
    #pragma unroll
    for (int fm = 0; fm < 2; fm++)
      #pragma unroll
      for (int fn = 0; fn < 2; fn++)
        oacc[fm][fn] = __builtin_amdgcn_mfma_f32_16x16x32_bf16(af[fm], bfr[fn], oacc[fm][fn], 0, 0, 0);
  }
  #pragma unroll
  for (int fm = 0; fm < 2; fm++)
    #pragma unroll
    for (int fn = 0; fn < 2; fn++)
      #pragma unroll
      for (int j = 0; j < 4; j++){
        int q  = wm * 32 + fm * 16 + (lane >> 4) * 4 + j;
        int hd = wn * 32 + fn * 16 + (lane & 15);
        aout[(size_t)(b * 64 + q) * 1024 + h * 64 + hd] = f2b(oacc[fm][fn][j]);
      }
}

// ---------------------------------------------------------------- launcher
extern "C" void kernel_launch(void* const* d_in, const int* in_sizes, int n_in,
                              void* d_out, int out_size, void* d_ws, size_t ws_size,
                              hipStream_t stream){
  const float* x     = (const float*)d_in[0];
  const float* wq    = (const float*)d_in[1];
  const float* bq    = (const float*)d_in[2];
  const float* wk    = (const float*)d_in[3];
  const float* bk    = (const float*)d_in[4];
  const float* wv    = (const float*)d_in[5];
  const float* bv    = (const float*)d_in[6];
  const float* wo    = (const float*)d_in[7];
  const float* bo    = (const float*)d_in[8];
  const float* sc_w  = (const float*)d_in[9];
  const float* sh1_w = (const float*)d_in[10];
  const float* sh1_b = (const float*)d_in[11];
  const float* ln1_g = (const float*)d_in[12];
  const float* ln1_b = (const float*)d_in[13];
  const float* sg_w  = (const float*)d_in[14];
  const float* sg_b  = (const float*)d_in[15];
  const float* ln2_g = (const float*)d_in[16];
  const float* ln2_b = (const float*)d_in[17];
  const float* swg_w = (const float*)d_in[18];

  char* ws = (char*)d_ws;
  size_t off = 0;
  auto alloc = [&](size_t bytes){ void* p = ws + off; off += (bytes + 255) & ~(size_t)255; return p; };
  u16*   xb    = (u16*)  alloc((size_t)MROWS * EMB * 2);     // x in bf16
  u16*   wqkvT = (u16*)  alloc((size_t)NQKV * EMB * 2);      // [3328][1024]
  float* qbias = (float*)alloc((size_t)NQKV * 4);
  u16*   woT   = (u16*)  alloc((size_t)1024 * 1024 * 2);
  u16*   swgT  = (u16*)  alloc((size_t)4096 * 256 * 2);
  u16*   qkvb  = (u16*)  alloc((size_t)MROWS * NQKV * 2);    // q|k|v|compressed bf16
  float* hid   = (float*)alloc((size_t)512 * 256 * 4);
  u16*   genb  = (u16*)  alloc((size_t)512 * 4096 * 2);      // = [8192][256] bf16
  float* smol  = (float*)alloc((size_t)8192 * 4096 * 4);     // [b*16+h][q*64+k]
  u16*   aout  = (u16*)  alloc((size_t)MROWS * 1024 * 2);    // attn output bf16

  // --- conversions / transposes (bf16, B^T layout) ---
  f32_to_bf16_v4<<<(MROWS * EMB) / 1024, 256, 0, stream>>>(x, xb);
  transpose_to_bf16<<<1024, 256, 0, stream>>>(wq,   wqkvT, 1024, 1024, 1024, 0);
  transpose_to_bf16<<<1024, 256, 0, stream>>>(wk,   wqkvT, 1024, 1024, 1024, 1024);
  transpose_to_bf16<<<1024, 256, 0, stream>>>(wv,   wqkvT, 1024, 1024, 1024, 2048);
  transpose_to_bf16<<<32,   256, 0, stream>>>(sc_w, wqkvT, 1024, 32,   1024, 3072);
  hipMemsetAsync(wqkvT + (size_t)3104 * 1024, 0, (size_t)(NQKV - 3104) * 1024 * 2, stream);
  transpose_to_bf16<<<1024, 256, 0, stream>>>(wo,    woT,  1024, 1024, 1024, 0);
  transpose_to_bf16<<<1024, 256, 0, stream>>>(swg_w, swgT, 256,  4096, 256,  0);
  build_qkv_bias<<<NQKV / 256, 256, 0, stream>>>(bq, bk, bv, qbias);

  // --- fused QKV + compressed projection: [32768,1024] @ [1024,3328] ---
  gemm256<1, 1><<<(MROWS / 256) * (NQKV / 256), 512, 0, stream>>>(
      xb, wqkvT, qbias, qkvb, MROWS, NQKV, 1024);

  // --- smolgen chain ---
  smol_hidden<<<BATCH / 2, 256, 0, stream>>>(qkvb, sh1_w, sh1_b, ln1_g, ln1_b, hid);
  smol_gen   <<<BATCH / 2, 256, 0, stream>>>(hid, sg_w, sg_b, ln2_g, ln2_b, genb);
  gemm256<0, 0><<<(8192 / 256) * (4096 / 256), 512, 0, stream>>>(
      genb, swgT, nullptr, smol, 8192, 4096, 256);

  // --- attention ---
  attn_fused<<<BATCH * NH, 256, 0, stream>>>(qkvb, smol, aout);

  // --- output projection: [32768,1024] @ [1024,1024] + bo -> fp32 d_out ---
  gemm256<0, 1><<<(MROWS / 256) * (1024 / 256), 512, 0, stream>>>(
      aout, woT, bo, d_out, MROWS, 1024, 1024);
}

// Round 3
// 900.814 us; speedup vs baseline: 1.0931x; 1.0468x over previous
//
#include <hip/hip_runtime.h>
#include <hip/hip_bf16.h>

typedef unsigned short u16;
typedef __attribute__((ext_vector_type(8))) short short8;
typedef __attribute__((ext_vector_type(4))) float f32x4;
typedef const __attribute__((address_space(1))) void GV;
typedef __attribute__((address_space(3))) void LV;
#define GLOAD16(g, l) __builtin_amdgcn_global_load_lds((GV*)(g), (LV*)(l), 16, 0, 0)
#define BAR() asm volatile("s_barrier" ::: "memory")

#define BATCH 512
#define LSEQ  64
#define EMB   1024
#define NH    16
#define NQKV  3328              // 1024 q | 1024 k | 1024 v | 32 sc | 224 pad (multiple of 256)
#define MROWS (BATCH*LSEQ)      // 32768

__device__ __forceinline__ u16 f2b(float f){
  __hip_bfloat16 h = __float2bfloat16(f);
  return *reinterpret_cast<u16*>(&h);
}
__device__ __forceinline__ float b2f(u16 u){
  return __uint_as_float(((unsigned)u) << 16);
}
__device__ __forceinline__ uint2 pack4(float4 v){
  unsigned lo = (unsigned)f2b(v.x) | ((unsigned)f2b(v.y) << 16);
  unsigned hi = (unsigned)f2b(v.z) | ((unsigned)f2b(v.w) << 16);
  return make_uint2(lo, hi);
}

// ---------------------------------------------------------------- conversions
__global__ __launch_bounds__(256) void f32_to_bf16_v4(const float* __restrict__ src,
                                                      u16* __restrict__ dst){
  size_t i = ((size_t)blockIdx.x * 256 + threadIdx.x) * 4;
  float4 v = *(const float4*)&src[i];
  *(uint2*)&dst[i] = pack4(v);
}

// dst[(dstRowOff+n)*dstLd + k] = bf16(src[k*N + n])   (src is [K][N] fp32)
__global__ __launch_bounds__(256) void transpose_to_bf16(const float* __restrict__ src,
                                                         u16* __restrict__ dst,
                                                         int K, int N, int dstLd, int dstRowOff){
  __shared__ float t[32][33];
  int nbx = N >> 5;
  int bx = blockIdx.x % nbx, by = blockIdx.x / nbx;
  int n0 = bx << 5, k0 = by << 5;
  int lx = threadIdx.x & 31, ly = threadIdx.x >> 5;   // 32 x 8
  #pragma unroll
  for (int i = 0; i < 32; i += 8)
    t[ly + i][lx] = src[(size_t)(k0 + ly + i) * N + n0 + lx];
  __syncthreads();
  #pragma unroll
  for (int i = 0; i < 32; i += 8)
    dst[(size_t)(dstRowOff + n0 + ly + i) * dstLd + k0 + lx] = f2b(t[lx][ly + i]);
}

__global__ __launch_bounds__(256) void build_qkv_bias(const float* __restrict__ bq,
                                                      const float* __restrict__ bk,
                                                      const float* __restrict__ bv,
                                                      float* __restrict__ out){
  int i = blockIdx.x * 256 + threadIdx.x;
  if (i < NQKV){
    float v = 0.f;
    if (i < 1024) v = bq[i];
    else if (i < 2048) v = bk[i - 1024];
    else if (i < 3072) v = bv[i - 2048];
    out[i] = v;
  }
}

// ---------------------------------------------------------------- 256x256 8-phase GEMM
// C[M,N] = A[M,K] @ Bt[N,K]^T (+bias[N]).  BM=BN=256, BK=64, 8 waves (2Mx4N),
// 128 KiB LDS double-buffer, T2 XOR-swizzle, counted vmcnt(6), setprio,
// bijective XCD swizzle.  ds_read balance 8/8/0/8 via cross-tile a2 prefetch:
//   p1: read B0+B1(t) [8]; stage A1(t+1); BAR; MFMA a2(A0) x B0 -> acc[0..3][0,1]
//   p2: read A1(t)    [8]; stage A0(t+2); BAR; MFMA a2(A0) x B1 -> acc[0..3][2,3]
//   p3:               [0]; stage B0(t+2); BAR; MFMA a (A1) x B1 -> acc[4..7][2,3]
//   p4: stage B1(t+2); vmcnt(6); BAR; read a2=A0(t+1) [8]; MFMA a x B0 -> acc[4..7][0,1]
// vmcnt(6) at p4 leaves exactly {A0,B0,B1}(t+2) in flight and confirms all of
// tile t+1 (incl. A0(t+1) staged at p2(t-1)) before the a2 read.
template<int OUT_BF16, int HAS_BIAS>
__global__ __launch_bounds__(512, 2) void gemm256(const u16* __restrict__ A,
                                                  const u16* __restrict__ Bt,
                                                  const float* __restrict__ bias,
                                                  void* __restrict__ Cv,
                                                  int M, int N, int K){
  __shared__ u16 lA[2][16384];   // [buf][half*8192 + row*64 + slot*8]
  __shared__ u16 lB[2][16384];
  const int ntn = N >> 8;
  const int nwg = gridDim.x, bid = blockIdx.x;
  const int qq = nwg >> 3, r8 = nwg & 7, xcd = bid & 7, kk = bid >> 3;
  const int wg = (xcd < r8 ? xcd * (qq + 1) : r8 * (qq + 1) + (xcd - r8) * qq) + kk;
  const int tm = wg / ntn, tn = wg % ntn;
  const int m0 = tm << 8, n0 = tn << 8;
  const int tid = threadIdx.x;
  const int w = tid >> 6, lane = tid & 63;
  const int wm = w >> 2, wn = w & 3;
  const int l15 = lane & 15, l4 = lane >> 4;

  // staging addresses: chunk ci = w*128 + j*64 + lane -> LDS slot (rh, s),
  // global k-chunk pre-swizzled = s ^ (rh&7).  j=+1 => rh+8 (same s).
  const int ci = w * 128 + lane;
  const int rh = ci >> 3, sl = ci & 7;
  const int gk = (sl ^ (rh & 7)) * 8;
  const unsigned aoff = (unsigned)((m0 + rh) * K + gk);
  const unsigned boff = (unsigned)((n0 + rh) * K + gk);

  auto stA = [&](int buf, int h, int kt){
    const u16* p = A + aoff + (size_t)(h * 128) * K + (size_t)kt * 64;
    GLOAD16(p,                &lA[buf][h * 8192 + (w * 128) * 8]);
    GLOAD16(p + (size_t)8 * K, &lA[buf][h * 8192 + (w * 128 + 64) * 8]);
  };
  auto stB = [&](int buf, int h, int kt){
    const u16* p = Bt + boff + (size_t)(h * 128) * K + (size_t)kt * 64;
    GLOAD16(p,                &lB[buf][h * 8192 + (w * 128) * 8]);
    GLOAD16(p + (size_t)8 * K, &lB[buf][h * 8192 + (w * 128 + 64) * 8]);
  };

  short8 a[4][2], a2[4][2], b[4][2];
  auto read_a2 = [&](const u16* la){   // A0-half rows f*32+wm*16+l15
    #pragma unroll
    for (int f = 0; f < 4; f++){
      int r = f * 32 + wm * 16 + l15;
      #pragma unroll
      for (int ks = 0; ks < 2; ks++){
        int c = ks * 4 + l4;
        a2[f][ks] = *(const short8*)&la[r * 64 + ((c ^ (r & 7)) * 8)];
      }
    }
  };

  const int nk = K >> 6;

  // prologue: tile0 {A0,B0,B1,A1}, tile1 {A0,B0,B1}; vmcnt(6) confirms tile0.
  stA(0, 0, 0); stB(0, 0, 0); stB(0, 1, 0); stA(0, 1, 0);
  stA(1, 0, 1); stB(1, 0, 1); stB(1, 1, 1);
  asm volatile("s_waitcnt vmcnt(6)" ::: "memory");
  BAR();
  read_a2(lA[0]);

  f32x4 acc[8][4] = {};

  for (int t = 0; t < nk; ++t){
    const int cur = t & 1;
    const u16* la = lA[cur];
    const u16* lb = lB[cur];

    // ---- phase 1: read B0+B1 (8); stage A1(t+1); MFMA A0xB0
    #pragma unroll
    for (int g = 0; g < 2; g++){
      int r = g * 64 + wn * 16 + l15;
      #pragma unroll
      for (int ks = 0; ks < 2; ks++){
        int c = ks * 4 + l4;
        b[g][ks] = *(const short8*)&lb[r * 64 + ((c ^ (r & 7)) * 8)];
      }
    }
    #pragma unroll
    for (int g = 2; g < 4; g++){
      int r = (g - 2) * 64 + wn * 16 + l15;
      #pragma unroll
      for (int ks = 0; ks < 2; ks++){
        int c = ks * 4 + l4;
        b[g][ks] = *(const short8*)&lb[8192 + r * 64 + ((c ^ (r & 7)) * 8)];
      }
    }
    if (t + 1 < nk) stA(cur ^ 1, 1, t + 1);
    BAR();
    __builtin_amdgcn_s_setprio(1);
    #pragma unroll
    for (int f = 0; f < 4; f++)
      #pragma unroll
      for (int g = 0; g < 2; g++)
        #pragma unroll
        for (int ks = 0; ks < 2; ks++)
          acc[f][g] = __builtin_amdgcn_mfma_f32_16x16x32_bf16(a2[f][ks], b[g][ks], acc[f][g], 0, 0, 0);
    __builtin_amdgcn_s_setprio(0);
    BAR();

    // ---- phase 2: read A1 (8); stage A0(t+2); MFMA A0xB1
    #pragma unroll
    for (int f = 0; f < 4; f++){
      int r = f * 32 + wm * 16 + l15;
      #pragma unroll
      for (int ks = 0; ks < 2; ks++){
        int c = ks * 4 + l4;
        a[f][ks] = *(const short8*)&la[8192 + r * 64 + ((c ^ (r & 7)) * 8)];
      }
    }
    if (t + 2 < nk) stA(cur, 0, t + 2);
    BAR();
    __builtin_amdgcn_s_setprio(1);
    #pragma unroll
    for (int f = 0; f < 4; f++)
      #pragma unroll
      for (int g = 2; g < 4; g++)
        #pragma unroll
        for (int ks = 0; ks < 2; ks++)
          acc[f][g] = __builtin_amdgcn_mfma_f32_16x16x32_bf16(a2[f][ks], b[g][ks], acc[f][g], 0, 0, 0);
    __builtin_amdgcn_s_setprio(0);
    BAR();

    // ---- phase 3: stage B0(t+2); MFMA A1xB1
    if (t + 2 < nk) stB(cur, 0, t + 2);
    BAR();
    __builtin_amdgcn_s_setprio(1);
    #pragma unroll
    for (int f = 0; f < 4; f++)
      #pragma unroll
      for (int g = 2; g < 4; g++)
        #pragma unroll
        for (int ks = 0; ks < 2; ks++)
          acc[f + 4][g] = __builtin_amdgcn_mfma_f32_16x16x32_bf16(a[f][ks], b[g][ks], acc[f + 4][g], 0, 0, 0);
    __builtin_amdgcn_s_setprio(0);
    BAR();

    // ---- phase 4: stage B1(t+2); boundary vmcnt; read a2=A0(t+1); MFMA A1xB0
    if (t + 2 < nk) stB(cur, 1, t + 2);
    if (t + 1 < nk){
      if (t + 2 < nk) asm volatile("s_waitcnt vmcnt(6)" ::: "memory");
      else            asm volatile("s_waitcnt vmcnt(0)" ::: "memory");
    }
    BAR();
    if (t + 1 < nk) read_a2(lA[cur ^ 1]);
    __builtin_amdgcn_s_setprio(1);
    #pragma unroll
    for (int f = 0; f < 4; f++)
      #pragma unroll
      for (int g = 0; g < 2; g++)
        #pragma unroll
        for (int ks = 0; ks < 2; ks++)
          acc[f + 4][g] = __builtin_amdgcn_mfma_f32_16x16x32_bf16(a[f][ks], b[g][ks], acc[f + 4][g], 0, 0, 0);
    __builtin_amdgcn_s_setprio(0);
    BAR();
  }

  // epilogue
  #pragma unroll
  for (int f = 0; f < 8; f++){
    #pragma unroll
    for (int g = 0; g < 4; g++){
      int col = n0 + g * 64 + wn * 16 + l15;
      float bv = HAS_BIAS ? bias[col] : 0.0f;
      #pragma unroll
      for (int j = 0; j < 4; j++){
        int row = m0 + f * 32 + wm * 16 + l4 * 4 + j;
        float v = acc[f][g][j] + bv;
        if (OUT_BF16) ((u16*)Cv)[(size_t)row * N + col] = f2b(v);
        else          ((float*)Cv)[(size_t)row * N + col] = v;
      }
    }
  }
}

// ---------------------------------------------------------------- smolgen hidden
// hidden[b][c] = LN256( silu(compressed[b] @ sh1_w + sh1_b) )
// 256 blocks x 512 threads; 2 batches/block; float4 weights; 8-way K-split.
__global__ __launch_bounds__(512) void smol_hidden(const u16* __restrict__ qkvb,
                                                   const float* __restrict__ sh1_w,
                                                   const float* __restrict__ sh1_b,
                                                   const float* __restrict__ ln1_g,
                                                   const float* __restrict__ ln1_b,
                                                   float* __restrict__ hidden){
  const int b0 = blockIdx.x * 2;
  const int tid = threadIdx.x;
  __shared__ u16 cb[2][2048];
  __shared__ float part[8][2][256];
  __shared__ float rs[16];
  {
    int bi = tid >> 8, rem = tid & 255;
    int l = rem >> 2, cc = rem & 3;
    *(short8*)&cb[bi][rem * 8] =
        *(const short8*)&qkvb[(size_t)((b0 + bi) * 64 + l) * NQKV + 3072 + cc * 8];
  }
  __syncthreads();
  const int g = tid >> 6;          // k-group: k in [g*256, g*256+256)
  const int c4 = (tid & 63) * 4;   // cols c4..c4+3
  float4 a0 = {0,0,0,0}, a1 = {0,0,0,0};
  for (int kk2 = 0; kk2 < 256; kk2++){
    int k = g * 256 + kk2;
    float4 wv = *(const float4*)&sh1_w[(size_t)k * 256 + c4];
    float x0 = b2f(cb[0][k]), x1 = b2f(cb[1][k]);
    a0.x += x0 * wv.x; a0.y += x0 * wv.y; a0.z += x0 * wv.z; a0.w += x0 * wv.w;
    a1.x += x1 * wv.x; a1.y += x1 * wv.y; a1.z += x1 * wv.z; a1.w += x1 * wv.w;
  }
  *(float4*)&part[g][0][c4] = a0;
  *(float4*)&part[g][1][c4] = a1;
  __syncthreads();
  // finalize: thread -> (bi = tid>>8, col = tid&255)
  const int bi = tid >> 8, col = tid & 255;
  float y = sh1_b[col];
  #pragma unroll
  for (int g2 = 0; g2 < 8; g2++) y += part[g2][bi][col];
  y = y / (1.f + __expf(-y));
  float s = y, q = y * y;
  #pragma unroll
  for (int o = 32; o > 0; o >>= 1){ s += __shfl_down(s, o); q += __shfl_down(q, o); }
  int wv_ = tid >> 6;
  if ((tid & 63) == 0){ rs[wv_ * 2] = s; rs[wv_ * 2 + 1] = q; }
  __syncthreads();
  float S = 0, Q = 0;
  #pragma unroll
  for (int w2 = 0; w2 < 4; w2++){ S += rs[(bi * 4 + w2) * 2]; Q += rs[(bi * 4 + w2) * 2 + 1]; }
  float m = S * (1.f / 256.f), var = Q * (1.f / 256.f) - m * m;
  hidden[(size_t)(b0 + bi) * 256 + col] =
      (y - m) * rsqrtf(var + 1e-3f) * ln1_g[col] + ln1_b[col];
}

// ---------------------------------------------------------------- smolgen gen
// gen[b][:4096] = LN4096( silu(hidden[b] @ sg_w + sg_b) ) -> bf16
// 256 blocks x 512 threads; 2 batches/block; float4 weights; 2 col-chunks/thread.
__global__ __launch_bounds__(512) void smol_gen(const float* __restrict__ hidden,
                                                const float* __restrict__ sg_w,
                                                const float* __restrict__ sg_b,
                                                const float* __restrict__ ln2_g,
                                                const float* __restrict__ ln2_b,
                                                u16* __restrict__ genb){
  const int b0 = blockIdx.x * 2;
  const int tid = threadIdx.x;
  __shared__ float hb[2][256];
  __shared__ float rs[32];
  if (tid < 512) hb[tid >> 8][tid & 255] = hidden[(size_t)(b0 + (tid >> 8)) * 256 + (tid & 255)];
  __syncthreads();
  const int c4 = tid * 4;   // chunk0 col, chunk1 col = 2048 + c4
  float4 A00 = {0,0,0,0}, A01 = {0,0,0,0}, A10 = {0,0,0,0}, A11 = {0,0,0,0};
  for (int k = 0; k < 256; k++){
    float h0 = hb[0][k], h1 = hb[1][k];
    float4 w0 = *(const float4*)&sg_w[(size_t)k * 4096 + c4];
    float4 w1 = *(const float4*)&sg_w[(size_t)k * 4096 + 2048 + c4];
    A00.x += h0 * w0.x; A00.y += h0 * w0.y; A00.z += h0 * w0.z; A00.w += h0 * w0.w;
    A01.x += h0 * w1.x; A01.y += h0 * w1.y; A01.z += h0 * w1.z; A01.w += h0 * w1.w;
    A10.x += h1 * w0.x; A10.y += h1 * w0.y; A10.z += h1 * w0.z; A10.w += h1 * w0.w;
    A11.x += h1 * w1.x; A11.y += h1 * w1.y; A11.z += h1 * w1.z; A11.w += h1 * w1.w;
  }
  float4 b0v = *(const float4*)&sg_b[c4];
  float4 b1v = *(const float4*)&sg_b[2048 + c4];
  float s0 = 0, q0 = 0, s1 = 0, q1 = 0;
  float* p;
  #pragma unroll
  for (int e = 0; e < 4; e++){
    p = (float*)&A00; float y = p[e] + ((float*)&b0v)[e]; y = y / (1.f + __expf(-y)); p[e] = y; s0 += y; q0 += y * y;
    p = (float*)&A01; y = p[e] + ((float*)&b1v)[e]; y = y / (1.f + __expf(-y)); p[e] = y; s0 += y; q0 += y * y;
    p = (float*)&A10; y = p[e] + ((float*)&b0v)[e]; y = y / (1.f + __expf(-y)); p[e] = y; s1 += y; q1 += y * y;
    p = (float*)&A11; y = p[e] + ((float*)&b1v)[e]; y = y / (1.f + __expf(-y)); p[e] = y; s1 += y; q1 += y * y;
  }
  #pragma unroll
  for (int o = 32; o > 0; o >>= 1){
    s0 += __shfl_down(s0, o); q0 += __shfl_down(q0, o);
    s1 += __shfl_down(s1, o); q1 += __shfl_down(q1, o);
  }
  int wv_ = tid >> 6;
  if ((tid & 63) == 0){ rs[wv_ * 4] = s0; rs[wv_ * 4 + 1] = q0; rs[wv_ * 4 + 2] = s1; rs[wv_ * 4 + 3] = q1; }
  __syncthreads();
  float S0 = 0, Q0 = 0, S1 = 0, Q1 = 0;
  #pragma unroll
  for (int w2 = 0; w2 < 8; w2++){
    S0 += rs[w2 * 4]; Q0 += rs[w2 * 4 + 1]; S1 += rs[w2 * 4 + 2]; Q1 += rs[w2 * 4 + 3];
  }
  float m0 = S0 * (1.f / 4096.f), v0 = Q0 * (1.f / 4096.f) - m0 * m0;
  float m1 = S1 * (1.f / 4096.f), v1 = Q1 * (1.f / 4096.f) - m1 * m1;
  float is0 = rsqrtf(v0 + 1e-3f), is1 = rsqrtf(v1 + 1e-3f);
  float4 g0 = *(const float4*)&ln2_g[c4],        gb0 = *(const float4*)&ln2_b[c4];
  float4 g1 = *(const float4*)&ln2_g[2048 + c4], gb1 = *(const float4*)&ln2_b[2048 + c4];
  float4 o00, o01, o10, o11;
  #pragma unroll
  for (int e = 0; e < 4; e++){
    ((float*)&o00)[e] = (((float*)&A00)[e] - m0) * is0 * ((float*)&g0)[e] + ((float*)&gb0)[e];
    ((float*)&o01)[e] = (((float*)&A01)[e] - m0) * is0 * ((float*)&g1)[e] + ((float*)&gb1)[e];
    ((float*)&o10)[e] = (((float*)&A10)[e] - m1) * is1 * ((float*)&g0)[e] + ((float*)&gb0)[e];
    ((float*)&o11)[e] = (((float*)&A11)[e] - m1) * is1 * ((float*)&g1)[e] + ((float*)&gb1)[e];
  }
  *(uint2*)&genb[(size_t)(b0    ) * 4096 + c4]        = pack4(o00);
  *(uint2*)&genb[(size_t)(b0    ) * 4096 + 2048 + c4] = pack4(o01);
  *(uint2*)&genb[(size_t)(b0 + 1) * 4096 + c4]        = pack4(o10);
  *(uint2*)&genb[(size_t)(b0 + 1) * 4096 + 2048 + c4] = pack4(o11);
}

// ---------------------------------------------------------------- fused attention
__global__ __launch_bounds__(256) void attn_fused(const u16* __restrict__ qkvb,
                                                  const float* __restrict__ smol,
                                                  u16* __restrict__ aout){
  const int bh = blockIdx.x;
  const int b = bh >> 4, h = bh & 15;
  __shared__ u16 qs[4096], kts[4096], vts[4096], ps[4096];
  __shared__ float Ss[64 * 68];
  const int tid = threadIdx.x, w = tid >> 6, lane = tid & 63;
  const int wm = w >> 1, wn = w & 1;

  const u16* qb = qkvb + (size_t)(b * 64) * NQKV + h * 64;
  const u16* kb = qb + 1024;
  const u16* vb = qb + 2048;

  #pragma unroll
  for (int i = 0; i < 2; i++){
    int c = i * 256 + tid;
    int r = c >> 3, cc = c & 7;
    int pc = cc ^ (r & 7);
    *(short8*)&qs [r * 64 + pc * 8] = *(const short8*)&qb[(size_t)r * NQKV + cc * 8];
    *(short8*)&kts[r * 64 + pc * 8] = *(const short8*)&kb[(size_t)r * NQKV + cc * 8];
    short8 vv = *(const short8*)&vb[(size_t)r * NQKV + cc * 8];
    #pragma unroll
    for (int j = 0; j < 8; j++){
      int hd = cc * 8 + j;
      int pcv = (r >> 3) ^ (hd & 7);
      vts[hd * 64 + pcv * 8 + (r & 7)] = (u16)vv[j];
    }
  }
  __syncthreads();

  f32x4 sacc[2][2] = {};
  #pragma unroll
  for (int ksi = 0; ksi < 2; ksi++){
    short8 af[2], bfr[2];
    #pragma unroll
    for (int f = 0; f < 2; f++){
      int ra = wm * 32 + f * 16 + (lane & 15);
      int ca = ksi * 4 + (lane >> 4);
      af[f]  = *(const short8*)&qs [ra * 64 + (ca ^ (ra & 7)) * 8];
      int rb = wn * 32 + f * 16 + (lane & 15);
      bfr[f] = *(const short8*)&kts[rb * 64 + (ca ^ (rb & 7)) * 8];
    }
    #pragma unroll
    for (int fm = 0; fm < 2; fm++)
      #pragma unroll
      for (int fn = 0; fn < 2; fn++)
        sacc[fm][fn] = __builtin_amdgcn_mfma_f32_16x16x32_bf16(af[fm], bfr[fn], sacc[fm][fn], 0, 0, 0);
  }
  const float* sm = smol + (size_t)bh * 4096;
  #pragma unroll
  for (int fm = 0; fm < 2; fm++)
    #pragma unroll
    for (int fn = 0; fn < 2; fn++)
      #pragma unroll
      for (int j = 0; j < 4; j++){
        int q  = wm * 32 + fm * 16 + (lane >> 4) * 4 + j;
        int kp = wn * 32 + fn * 16 + (lane & 15);
        Ss[q * 68 + kp] = sacc[fm][fn][j] * 0.125f + sm[q * 64 + kp];
      }
  __syncthreads();

  {
    int row = w * 16 + (lane >> 2);
    int sub = lane & 3;
    float* srow = &Ss[row * 68];
    float vals[16];
    float mx = -3.4e38f;
    #pragma unroll
    for (int i = 0; i < 16; i++){ vals[i] = srow[sub * 16 + i]; mx = fmaxf(mx, vals[i]); }
    mx = fmaxf(mx, __shfl_xor(mx, 1));
    mx = fmaxf(mx, __shfl_xor(mx, 2));
    float s = 0.f;
    #pragma unroll
    for (int i = 0; i < 16; i++){ vals[i] = __expf(vals[i] - mx); s += vals[i]; }
    s += __shfl_xor(s, 1);
    s += __shfl_xor(s, 2);
    float rinv = 1.f / s;
    short8 o0, o1;
    #pragma unroll
    for (int i = 0; i < 8; i++){ o0[i] = (short)f2b(vals[i] * rinv); o1[i] = (short)f2b(vals[8 + i] * rinv); }
    int c0 = sub * 2, c1 = sub * 2 + 1;
    *(short8*)&ps[row * 64 + (c0 ^ (row & 7)) * 8] = o0;
    *(short8*)&ps[row * 64 + (c1 ^ (row & 7)) * 8] = o1;
  }
  __syncthreads();

  f32x4 oacc[2][2] = {};
  #pragma unroll
  for (int ksi = 0; ksi < 2; ksi++){
    short8 af[2], bfr[2];
    #pragma unroll
    for (int f = 0; f < 2; f++){
      int ra = wm * 32 + f * 16 + (lane & 15);
      int ca = ksi * 4 + (lane >> 4);
      af[f]  = *(const short8*)&ps [ra * 64 + (ca ^ (ra & 7)) * 8];
      int rb = wn * 32 + f * 16 + (lane & 15);
      bfr[f] = *(const short8*)&vts[rb * 64 + (ca ^ (rb & 7)) * 8];
    }
    #pragma unroll
    for (int fm = 0; fm < 2; fm++)
      #pragma unroll
      for (int fn = 0; fn < 2; fn++)
        oacc[fm][fn] = __builtin_amdgcn_mfma_f32_16x16x32_bf16(af[fm], bfr[fn], oacc[fm][fn], 0, 0, 0);
  }
  #pragma unroll
  for (int fm = 0; fm < 2; fm++)
    #pragma unroll
    for (int fn = 0; fn < 2; fn++)
      #pragma unroll
      for (int j = 0; j < 4; j++){
        int q  = wm * 32 + fm * 16 + (lane >> 4) * 4 + j;
        int hd = wn * 32 + fn * 16 + (lane & 15);
        aout[(size_t)(b * 64 + q) * 1024 + h * 64 + hd] = f2b(oacc[fm][fn][j]);
      }
}

// ---------------------------------------------------------------- launcher
extern "C" void kernel_launch(void* const* d_in, const int* in_sizes, int n_in,
                              void* d_out, int out_size, void* d_ws, size_t ws_size,
                              hipStream_t stream){
  const float* x     = (const float*)d_in[0];
  const float* wq    = (const float*)d_in[1];
  const float* bq    = (const float*)d_in[2];
  const float* wk    = (const float*)d_in[3];
  const float* bk    = (const float*)d_in[4];
  const float* wv    = (const float*)d_in[5];
  const float* bv    = (const float*)d_in[6];
  const float* wo    = (const float*)d_in[7];
  const float* bo    = (const float*)d_in[8];
  const float* sc_w  = (const float*)d_in[9];
  const float* sh1_w = (const float*)d_in[10];
  const float* sh1_b = (const float*)d_in[11];
  const float* ln1_g = (const float*)d_in[12];
  const float* ln1_b = (const float*)d_in[13];
  const float* sg_w  = (const float*)d_in[14];
  const float* sg_b  = (const float*)d_in[15];
  const float* ln2_g = (const float*)d_in[16];
  const float* ln2_b = (const float*)d_in[17];
  const float* swg_w = (const float*)d_in[18];

  char* ws = (char*)d_ws;
  size_t off = 0;
  auto alloc = [&](size_t bytes){ void* p = ws + off; off += (bytes + 255) & ~(size_t)255; return p; };
  u16*   xb    = (u16*)  alloc((size_t)MROWS * EMB * 2);
  u16*   wqkvT = (u16*)  alloc((size_t)NQKV * EMB * 2);
  float* qbias = (float*)alloc((size_t)NQKV * 4);
  u16*   woT   = (u16*)  alloc((size_t)1024 * 1024 * 2);
  u16*   swgT  = (u16*)  alloc((size_t)4096 * 256 * 2);
  u16*   qkvb  = (u16*)  alloc((size_t)MROWS * NQKV * 2);
  float* hid   = (float*)alloc((size_t)512 * 256 * 4);
  u16*   genb  = (u16*)  alloc((size_t)512 * 4096 * 2);
  float* smol  = (float*)alloc((size_t)8192 * 4096 * 4);
  u16*   aout  = (u16*)  alloc((size_t)MROWS * 1024 * 2);

  f32_to_bf16_v4<<<(MROWS * EMB) / 1024, 256, 0, stream>>>(x, xb);
  transpose_to_bf16<<<1024, 256, 0, stream>>>(wq,   wqkvT, 1024, 1024, 1024, 0);
  transpose_to_bf16<<<1024, 256, 0, stream>>>(wk,   wqkvT, 1024, 1024, 1024, 1024);
  transpose_to_bf16<<<1024, 256, 0, stream>>>(wv,   wqkvT, 1024, 1024, 1024, 2048);
  transpose_to_bf16<<<32,   256, 0, stream>>>(sc_w, wqkvT, 1024, 32,   1024, 3072);
  hipMemsetAsync(wqkvT + (size_t)3104 * 1024, 0, (size_t)(NQKV - 3104) * 1024 * 2, stream);
  transpose_to_bf16<<<1024, 256, 0, stream>>>(wo,    woT,  1024, 1024, 1024, 0);
  transpose_to_bf16<<<1024, 256, 0, stream>>>(swg_w, swgT, 256,  4096, 256,  0);
  build_qkv_bias<<<NQKV / 256, 256, 0, stream>>>(bq, bk, bv, qbias);

  gemm256<1, 1><<<(MROWS / 256) * (NQKV / 256), 512, 0, stream>>>(
      xb, wqkvT, qbias, qkvb, MROWS, NQKV, 1024);

  smol_hidden<<<BATCH / 2, 512, 0, stream>>>(qkvb, sh1_w, sh1_b, ln1_g, ln1_b, hid);
  smol_gen   <<<BATCH / 2, 512, 0, stream>>>(hid, sg_w, sg_b, ln2_g, ln2_b, genb);
  gemm256<0, 0><<<(8192 / 256) * (4096 / 256), 512, 0, stream>>>(
      genb, swgT, nullptr, smol, 8192, 4096, 256);

  attn_fused<<<BATCH * NH, 256, 0, stream>>>(qkvb, smol, aout);

  gemm256<0, 1><<<(MROWS / 256) * (1024 / 256), 512, 0, stream>>>(
      aout, woT, bo, d_out, MROWS, 1024, 1024);
}

// Round 5
// 807.308 us; speedup vs baseline: 1.2197x; 1.1158x over previous
//
#include <hip/hip_runtime.h>
#include <hip/hip_bf16.h>

typedef unsigned short u16;
typedef __attribute__((ext_vector_type(8))) short short8;
typedef __attribute__((ext_vector_type(4))) float f32x4;
typedef const __attribute__((address_space(1))) void GV;
typedef __attribute__((address_space(3))) void LV;
#define GLOAD16(g, l) __builtin_amdgcn_global_load_lds((GV*)(g), (LV*)(l), 16, 0, 0)
#define BAR() asm volatile("s_barrier" ::: "memory")

#define BATCH 512
#define LSEQ  64
#define EMB   1024
#define NH    16
#define NQKV  3328              // 1024 q | 1024 k | 1024 v | 32 sc | 224 pad (multiple of 256)
#define MROWS (BATCH*LSEQ)      // 32768

__device__ __forceinline__ u16 f2b(float f){
  __hip_bfloat16 h = __float2bfloat16(f);
  return *reinterpret_cast<u16*>(&h);
}
__device__ __forceinline__ float b2f(u16 u){
  return __uint_as_float(((unsigned)u) << 16);
}
__device__ __forceinline__ uint2 pack4(float4 v){
  unsigned lo = (unsigned)f2b(v.x) | ((unsigned)f2b(v.y) << 16);
  unsigned hi = (unsigned)f2b(v.z) | ((unsigned)f2b(v.w) << 16);
  return make_uint2(lo, hi);
}

// ---------------------------------------------------------------- fused prep
// One kernel, block-range sections:
//  [0,32768)        x -> xb (bf16, float4/thread)
//  [32768,33792)    wq  -> wqkvT rows 0..1023      (transpose)
//  [33792,34816)    wk  -> wqkvT rows 1024..2047
//  [34816,35840)    wv  -> wqkvT rows 2048..3071
//  [35840,35872)    sc_w-> wqkvT rows 3072..3103
//  [35872,36896)    wo  -> woT
//  [36896,37920)    swg_w -> swgT
//  [37920,38144)    zero pad rows 3104..3327 of wqkvT
//  [38144,38157)    qbias build
__device__ __forceinline__ void tpose(const float* __restrict__ src, u16* __restrict__ dst,
                                      int K, int N, int dstLd, int dstRowOff,
                                      int blk, int tid, float (*t)[33]){
  int nbx = N >> 5;
  int bx = blk % nbx, by = blk / nbx;
  int n0 = bx << 5, k0 = by << 5;
  int lx = tid & 31, ly = tid >> 5;   // 32 x 8
  #pragma unroll
  for (int i = 0; i < 32; i += 8)
    t[ly + i][lx] = src[(size_t)(k0 + ly + i) * N + n0 + lx];
  __syncthreads();
  #pragma unroll
  for (int i = 0; i < 32; i += 8)
    dst[(size_t)(dstRowOff + n0 + ly + i) * dstLd + k0 + lx] = f2b(t[lx][ly + i]);
}

#define PREP_BLOCKS 38157
__global__ __launch_bounds__(256) void prep_all(const float* __restrict__ x, u16* __restrict__ xb,
                                                const float* __restrict__ wq, const float* __restrict__ wk,
                                                const float* __restrict__ wv, const float* __restrict__ sc_w,
                                                const float* __restrict__ wo, const float* __restrict__ swg_w,
                                                u16* __restrict__ wqkvT, u16* __restrict__ woT,
                                                u16* __restrict__ swgT,
                                                const float* __restrict__ bq, const float* __restrict__ bk,
                                                const float* __restrict__ bv, float* __restrict__ qbias){
  __shared__ float t[32][33];
  const int blk = blockIdx.x, tid = threadIdx.x;
  if (blk < 32768){
    size_t i = ((size_t)blk * 256 + tid) * 4;
    float4 v = *(const float4*)&x[i];
    *(uint2*)&xb[i] = pack4(v);
  } else if (blk < 33792){
    tpose(wq,   wqkvT, 1024, 1024, 1024, 0,    blk - 32768, tid, t);
  } else if (blk < 34816){
    tpose(wk,   wqkvT, 1024, 1024, 1024, 1024, blk - 33792, tid, t);
  } else if (blk < 35840){
    tpose(wv,   wqkvT, 1024, 1024, 1024, 2048, blk - 34816, tid, t);
  } else if (blk < 35872){
    tpose(sc_w, wqkvT, 1024, 32,   1024, 3072, blk - 35840, tid, t);
  } else if (blk < 36896){
    tpose(wo,   woT,   1024, 1024, 1024, 0,    blk - 35872, tid, t);
  } else if (blk < 37920){
    tpose(swg_w, swgT, 256,  4096, 256,  0,    blk - 36896, tid, t);
  } else if (blk < 38144){
    size_t i = (size_t)(blk - 37920) * 1024 + tid * 4;
    *(uint2*)&wqkvT[(size_t)3104 * 1024 + i] = make_uint2(0, 0);
  } else {
    int i = (blk - 38144) * 256 + tid;
    if (i < NQKV){
      float v = 0.f;
      if (i < 1024) v = bq[i];
      else if (i < 2048) v = bk[i - 1024];
      else if (i < 3072) v = bv[i - 2048];
      qbias[i] = v;
    }
  }
}

// ---------------------------------------------------------------- 256x256 8-phase GEMM
// (exact R2 schedule — known good: 268us QKV, MfmaUtil 36%, 0 bank conflicts)
// C[M,N] = A[M,K] @ Bt[N,K]^T (+bias[N]).  BM=BN=256, BK=64, 8 waves (2Mx4N),
// 128 KiB LDS double-buffer, T2 XOR-swizzle, counted vmcnt(6), setprio,
// bijective XCD swizzle.  Phases: p1 (A0xB0, ds A0+B0, stage A1(t+1));
// p2 (A0xB1, ds B1, stage A0(t+2)); p3 (A1xB1, ds A1, stage B0(t+2));
// p4 (A1xB0, stage B1(t+2), vmcnt(6) boundary wait).
template<int OUT_BF16, int HAS_BIAS>
__global__ __launch_bounds__(512, 2) void gemm256(const u16* __restrict__ A,
                                                  const u16* __restrict__ Bt,
                                                  const float* __restrict__ bias,
                                                  void* __restrict__ Cv,
                                                  int M, int N, int K){
  __shared__ u16 lA[2][16384];   // [buf][half*8192 + row*64 + swz_slot*8]
  __shared__ u16 lB[2][16384];
  const int ntn = N >> 8;
  const int nwg = gridDim.x, bid = blockIdx.x;
  const int qq = nwg >> 3, r8 = nwg & 7, xcd = bid & 7, kk = bid >> 3;
  const int wg = (xcd < r8 ? xcd * (qq + 1) : r8 * (qq + 1) + (xcd - r8) * qq) + kk;
  const int tm = wg / ntn, tn = wg % ntn;
  const int m0 = tm << 8, n0 = tn << 8;
  const int tid = threadIdx.x;
  const int w = tid >> 6, lane = tid & 63;
  const int wm = w >> 2, wn = w & 3;
  const int l15 = lane & 15, l4 = lane >> 4;

  size_t ga[2][2], gb[2][2];
  #pragma unroll
  for (int j = 0; j < 2; j++){
    int ci = w * 128 + j * 64 + lane;
    int rh = ci >> 3, s = ci & 7;
    int gk = (s ^ (rh & 7)) * 8;
    #pragma unroll
    for (int h = 0; h < 2; h++){
      ga[h][j] = (size_t)(m0 + h * 128 + rh) * K + gk;
      gb[h][j] = (size_t)(n0 + h * 128 + rh) * K + gk;
    }
  }
  const int nk = K >> 6;

  auto stA = [&](int buf, int h, int kt){
    #pragma unroll
    for (int j = 0; j < 2; j++)
      GLOAD16(A + ga[h][j] + (size_t)kt * 64, &lA[buf][h * 8192 + (w * 128 + j * 64) * 8]);
  };
  auto stB = [&](int buf, int h, int kt){
    #pragma unroll
    for (int j = 0; j < 2; j++)
      GLOAD16(Bt + gb[h][j] + (size_t)kt * 64, &lB[buf][h * 8192 + (w * 128 + j * 64) * 8]);
  };

  // prologue: tile0 {A0,B0,B1,A1}, tile1 {A0,B0,B1}; vmcnt(6) confirms tile0.
  stA(0, 0, 0); stB(0, 0, 0); stB(0, 1, 0); stA(0, 1, 0);
  stA(1, 0, 1); stB(1, 0, 1); stB(1, 1, 1);
  asm volatile("s_waitcnt vmcnt(6)" ::: "memory");
  BAR();

  f32x4 acc[8][4] = {};
  short8 a[4][2], b[4][2];

  for (int t = 0; t < nk; ++t){
    const int cur = t & 1;
    const u16* la = lA[cur];
    const u16* lb = lB[cur];

    // ---- phase 1: ds A0(8) + B0(4); stage A1(t+1); MFMA A0xB0
    #pragma unroll
    for (int f = 0; f < 4; f++){
      int r = f * 32 + wm * 16 + l15;
      #pragma unroll
      for (int ks = 0; ks < 2; ks++){
        int c = ks * 4 + l4;
        a[f][ks] = *(const short8*)&la[r * 64 + ((c ^ (r & 7)) * 8)];
      }
    }
    #pragma unroll
    for (int g = 0; g < 2; g++){
      int r = g * 64 + wn * 16 + l15;
      #pragma unroll
      for (int ks = 0; ks < 2; ks++){
        int c = ks * 4 + l4;
        b[g][ks] = *(const short8*)&lb[r * 64 + ((c ^ (r & 7)) * 8)];
      }
    }
    if (t + 1 < nk) stA(cur ^ 1, 1, t + 1);
    BAR();
    __builtin_amdgcn_s_setprio(1);
    #pragma unroll
    for (int f = 0; f < 4; f++)
      #pragma unroll
      for (int g = 0; g < 2; g++)
        #pragma unroll
        for (int ks = 0; ks < 2; ks++)
          acc[f][g] = __builtin_amdgcn_mfma_f32_16x16x32_bf16(a[f][ks], b[g][ks], acc[f][g], 0, 0, 0);
    __builtin_amdgcn_s_setprio(0);
    BAR();

    // ---- phase 2: ds B1(4); stage A0(t+2); MFMA A0xB1
    #pragma unroll
    for (int g = 2; g < 4; g++){
      int r = (g - 2) * 64 + wn * 16 + l15;
      #pragma unroll
      for (int ks = 0; ks < 2; ks++){
        int c = ks * 4 + l4;
        b[g][ks] = *(const short8*)&lb[8192 + r * 64 + ((c ^ (r & 7)) * 8)];
      }
    }
    if (t + 2 < nk) stA(cur, 0, t + 2);
    BAR();
    __builtin_amdgcn_s_setprio(1);
    #pragma unroll
    for (int f = 0; f < 4; f++)
      #pragma unroll
      for (int g = 2; g < 4; g++)
        #pragma unroll
        for (int ks = 0; ks < 2; ks++)
          acc[f][g] = __builtin_amdgcn_mfma_f32_16x16x32_bf16(a[f][ks], b[g][ks], acc[f][g], 0, 0, 0);
    __builtin_amdgcn_s_setprio(0);
    BAR();

    // ---- phase 3: ds A1(8); stage B0(t+2); MFMA A1xB1
    #pragma unroll
    for (int f = 0; f < 4; f++){
      int r = f * 32 + wm * 16 + l15;   // rows 128..255 live at lA[...][8192+]
      #pragma unroll
      for (int ks = 0; ks < 2; ks++){
        int c = ks * 4 + l4;
        a[f][ks] = *(const short8*)&la[8192 + r * 64 + ((c ^ (r & 7)) * 8)];
      }
    }
    if (t + 2 < nk) stB(cur, 0, t + 2);
    BAR();
    __builtin_amdgcn_s_setprio(1);
    #pragma unroll
    for (int f = 0; f < 4; f++)
      #pragma unroll
      for (int g = 2; g < 4; g++)
        #pragma unroll
        for (int ks = 0; ks < 2; ks++)
          acc[f + 4][g] = __builtin_amdgcn_mfma_f32_16x16x32_bf16(a[f][ks], b[g][ks], acc[f + 4][g], 0, 0, 0);
    __builtin_amdgcn_s_setprio(0);
    BAR();

    // ---- phase 4: stage B1(t+2); boundary vmcnt; MFMA A1xB0
    if (t + 2 < nk) stB(cur, 1, t + 2);
    if (t + 1 < nk){
      if (t + 2 < nk) asm volatile("s_waitcnt vmcnt(6)" ::: "memory");
      else            asm volatile("s_waitcnt vmcnt(0)" ::: "memory");
    }
    BAR();
    __builtin_amdgcn_s_setprio(1);
    #pragma unroll
    for (int f = 0; f < 4; f++)
      #pragma unroll
      for (int g = 0; g < 2; g++)
        #pragma unroll
        for (int ks = 0; ks < 2; ks++)
          acc[f + 4][g] = __builtin_amdgcn_mfma_f32_16x16x32_bf16(a[f][ks], b[g][ks], acc[f + 4][g], 0, 0, 0);
    __builtin_amdgcn_s_setprio(0);
    BAR();
  }

  // epilogue
  #pragma unroll
  for (int f = 0; f < 8; f++){
    #pragma unroll
    for (int g = 0; g < 4; g++){
      int col = n0 + g * 64 + wn * 16 + l15;
      float bv = HAS_BIAS ? bias[col] : 0.0f;
      #pragma unroll
      for (int j = 0; j < 4; j++){
        int row = m0 + f * 32 + wm * 16 + l4 * 4 + j;
        float v = acc[f][g][j] + bv;
        if (OUT_BF16) ((u16*)Cv)[(size_t)row * N + col] = f2b(v);
        else          ((float*)Cv)[(size_t)row * N + col] = v;
      }
    }
  }
}

// ---------------------------------------------------------------- smolgen hidden
// hidden[b][c] = LN256( silu(compressed[b] @ sh1_w + sh1_b) )
// 256 blocks x 512 threads; 2 batches/block; float4 weights; 8-way K-split.
__global__ __launch_bounds__(512) void smol_hidden(const u16* __restrict__ qkvb,
                                                   const float* __restrict__ sh1_w,
                                                   const float* __restrict__ sh1_b,
                                                   const float* __restrict__ ln1_g,
                                                   const float* __restrict__ ln1_b,
                                                   float* __restrict__ hidden){
  const int b0 = blockIdx.x * 2;
  const int tid = threadIdx.x;
  __shared__ u16 cb[2][2048];
  __shared__ float part[8][2][256];
  __shared__ float rs[16];
  {
    int bi = tid >> 8, rem = tid & 255;
    int l = rem >> 2, cc = rem & 3;
    *(short8*)&cb[bi][rem * 8] =
        *(const short8*)&qkvb[(size_t)((b0 + bi) * 64 + l) * NQKV + 3072 + cc * 8];
  }
  __syncthreads();
  const int g = tid >> 6;          // k-group: k in [g*256, g*256+256)
  const int c4 = (tid & 63) * 4;   // cols c4..c4+3
  float4 a0 = {0,0,0,0}, a1 = {0,0,0,0};
  for (int kk2 = 0; kk2 < 256; kk2++){
    int k = g * 256 + kk2;
    float4 wv = *(const float4*)&sh1_w[(size_t)k * 256 + c4];
    float x0 = b2f(cb[0][k]), x1 = b2f(cb[1][k]);
    a0.x += x0 * wv.x; a0.y += x0 * wv.y; a0.z += x0 * wv.z; a0.w += x0 * wv.w;
    a1.x += x1 * wv.x; a1.y += x1 * wv.y; a1.z += x1 * wv.z; a1.w += x1 * wv.w;
  }
  *(float4*)&part[g][0][c4] = a0;
  *(float4*)&part[g][1][c4] = a1;
  __syncthreads();
  const int bi = tid >> 8, col = tid & 255;
  float y = sh1_b[col];
  #pragma unroll
  for (int g2 = 0; g2 < 8; g2++) y += part[g2][bi][col];
  y = y / (1.f + __expf(-y));
  float s = y, q = y * y;
  #pragma unroll
  for (int o = 32; o > 0; o >>= 1){ s += __shfl_down(s, o); q += __shfl_down(q, o); }
  int wv_ = tid >> 6;
  if ((tid & 63) == 0){ rs[wv_ * 2] = s; rs[wv_ * 2 + 1] = q; }
  __syncthreads();
  float S = 0, Q = 0;
  #pragma unroll
  for (int w2 = 0; w2 < 4; w2++){ S += rs[(bi * 4 + w2) * 2]; Q += rs[(bi * 4 + w2) * 2 + 1]; }
  float m = S * (1.f / 256.f), var = Q * (1.f / 256.f) - m * m;
  hidden[(size_t)(b0 + bi) * 256 + col] =
      (y - m) * rsqrtf(var + 1e-3f) * ln1_g[col] + ln1_b[col];
}

// ---------------------------------------------------------------- smolgen gen
// gen[b][:4096] = LN4096( silu(hidden[b] @ sg_w + sg_b) ) -> bf16
// 256 blocks x 512 threads; 2 batches/block; float4 weights; 2 col-chunks/thread.
__global__ __launch_bounds__(512) void smol_gen(const float* __restrict__ hidden,
                                                const float* __restrict__ sg_w,
                                                const float* __restrict__ sg_b,
                                                const float* __restrict__ ln2_g,
                                                const float* __restrict__ ln2_b,
                                                u16* __restrict__ genb){
  const int b0 = blockIdx.x * 2;
  const int tid = threadIdx.x;
  __shared__ float hb[2][256];
  __shared__ float rs[32];
  if (tid < 512) hb[tid >> 8][tid & 255] = hidden[(size_t)(b0 + (tid >> 8)) * 256 + (tid & 255)];
  __syncthreads();
  const int c4 = tid * 4;   // chunk0 col, chunk1 col = 2048 + c4
  float4 A00 = {0,0,0,0}, A01 = {0,0,0,0}, A10 = {0,0,0,0}, A11 = {0,0,0,0};
  for (int k = 0; k < 256; k++){
    float h0 = hb[0][k], h1 = hb[1][k];
    float4 w0 = *(const float4*)&sg_w[(size_t)k * 4096 + c4];
    float4 w1 = *(const float4*)&sg_w[(size_t)k * 4096 + 2048 + c4];
    A00.x += h0 * w0.x; A00.y += h0 * w0.y; A00.z += h0 * w0.z; A00.w += h0 * w0.w;
    A01.x += h0 * w1.x; A01.y += h0 * w1.y; A01.z += h0 * w1.z; A01.w += h0 * w1.w;
    A10.x += h1 * w0.x; A10.y += h1 * w0.y; A10.z += h1 * w0.z; A10.w += h1 * w0.w;
    A11.x += h1 * w1.x; A11.y += h1 * w1.y; A11.z += h1 * w1.z; A11.w += h1 * w1.w;
  }
  float4 b0v = *(const float4*)&sg_b[c4];
  float4 b1v = *(const float4*)&sg_b[2048 + c4];
  float s0 = 0, q0 = 0, s1 = 0, q1 = 0;
  float* p;
  #pragma unroll
  for (int e = 0; e < 4; e++){
    p = (float*)&A00; float y = p[e] + ((float*)&b0v)[e]; y = y / (1.f + __expf(-y)); p[e] = y; s0 += y; q0 += y * y;
    p = (float*)&A01; y = p[e] + ((float*)&b1v)[e]; y = y / (1.f + __expf(-y)); p[e] = y; s0 += y; q0 += y * y;
    p = (float*)&A10; y = p[e] + ((float*)&b0v)[e]; y = y / (1.f + __expf(-y)); p[e] = y; s1 += y; q1 += y * y;
    p = (float*)&A11; y = p[e] + ((float*)&b1v)[e]; y = y / (1.f + __expf(-y)); p[e] = y; s1 += y; q1 += y * y;
  }
  #pragma unroll
  for (int o = 32; o > 0; o >>= 1){
    s0 += __shfl_down(s0, o); q0 += __shfl_down(q0, o);
    s1 += __shfl_down(s1, o); q1 += __shfl_down(q1, o);
  }
  int wv_ = tid >> 6;
  if ((tid & 63) == 0){ rs[wv_ * 4] = s0; rs[wv_ * 4 + 1] = q0; rs[wv_ * 4 + 2] = s1; rs[wv_ * 4 + 3] = q1; }
  __syncthreads();
  float S0 = 0, Q0 = 0, S1 = 0, Q1 = 0;
  #pragma unroll
  for (int w2 = 0; w2 < 8; w2++){
    S0 += rs[w2 * 4]; Q0 += rs[w2 * 4 + 1]; S1 += rs[w2 * 4 + 2]; Q1 += rs[w2 * 4 + 3];
  }
  float m0 = S0 * (1.f / 4096.f), v0 = Q0 * (1.f / 4096.f) - m0 * m0;
  float m1 = S1 * (1.f / 4096.f), v1 = Q1 * (1.f / 4096.f) - m1 * m1;
  float is0 = rsqrtf(v0 + 1e-3f), is1 = rsqrtf(v1 + 1e-3f);
  float4 g0 = *(const float4*)&ln2_g[c4],        gb0 = *(const float4*)&ln2_b[c4];
  float4 g1 = *(const float4*)&ln2_g[2048 + c4], gb1 = *(const float4*)&ln2_b[2048 + c4];
  float4 o00, o01, o10, o11;
  #pragma unroll
  for (int e = 0; e < 4; e++){
    ((float*)&o00)[e] = (((float*)&A00)[e] - m0) * is0 * ((float*)&g0)[e] + ((float*)&gb0)[e];
    ((float*)&o01)[e] = (((float*)&A01)[e] - m0) * is0 * ((float*)&g1)[e] + ((float*)&gb1)[e];
    ((float*)&o10)[e] = (((float*)&A10)[e] - m1) * is1 * ((float*)&g0)[e] + ((float*)&gb0)[e];
    ((float*)&o11)[e] = (((float*)&A11)[e] - m1) * is1 * ((float*)&g1)[e] + ((float*)&gb1)[e];
  }
  *(uint2*)&genb[(size_t)(b0    ) * 4096 + c4]        = pack4(o00);
  *(uint2*)&genb[(size_t)(b0    ) * 4096 + 2048 + c4] = pack4(o01);
  *(uint2*)&genb[(size_t)(b0 + 1) * 4096 + c4]        = pack4(o10);
  *(uint2*)&genb[(size_t)(b0 + 1) * 4096 + 2048 + c4] = pack4(o11);
}

// ---------------------------------------------------------------- fused attention
__global__ __launch_bounds__(256) void attn_fused(const u16* __restrict__ qkvb,
                                                  const float* __restrict__ smol,
                                                  u16* __restrict__ aout){
  const int bh = blockIdx.x;
  const int b = bh >> 4, h = bh & 15;
  __shared__ u16 qs[4096], kts[4096], vts[4096], ps[4096];
  __shared__ float Ss[64 * 68];
  const int tid = threadIdx.x, w = tid >> 6, lane = tid & 63;
  const int wm = w >> 1, wn = w & 1;

  const u16* qb = qkvb + (size_t)(b * 64) * NQKV + h * 64;
  const u16* kb = qb + 1024;
  const u16* vb = qb + 2048;

  #pragma unroll
  for (int i = 0; i < 2; i++){
    int c = i * 256 + tid;
    int r = c >> 3, cc = c & 7;
    int pc = cc ^ (r & 7);
    *(short8*)&qs [r * 64 + pc * 8] = *(const short8*)&qb[(size_t)r * NQKV + cc * 8];
    *(short8*)&kts[r * 64 + pc * 8] = *(const short8*)&kb[(size_t)r * NQKV + cc * 8];
    short8 vv = *(const short8*)&vb[(size_t)r * NQKV + cc * 8];
    #pragma unroll
    for (int j = 0; j < 8; j++){
      int hd = cc * 8 + j;
      int pcv = (r >> 3) ^ (hd & 7);
      vts[hd * 64 + pcv * 8 + (r & 7)] = (u16)vv[j];
    }
  }
  __syncthreads();

  f32x4 sacc[2][2] = {};
  #pragma unroll
  for (int ksi = 0; ksi < 2; ksi++){
    short8 af[2], bfr[2];
    #pragma unroll
    for (int f = 0; f < 2; f++){
      int ra = wm * 32 + f * 16 + (lane & 15);
      int ca = ksi * 4 + (lane >> 4);
      af[f]  = *(const short8*)&qs [ra * 64 + (ca ^ (ra & 7)) * 8];
      int rb = wn * 32 + f * 16 + (lane & 15);
      bfr[f] = *(const short8*)&kts[rb * 64 + (ca ^ (rb & 7)) * 8];
    }
    #pragma unroll
    for (int fm = 0; fm < 2; fm++)
      #pragma unroll
      for (int fn = 0; fn < 2; fn++)
        sacc[fm][fn] = __builtin_amdgcn_mfma_f32_16x16x32_bf16(af[fm], bfr[fn], sacc[fm][fn], 0, 0, 0);
  }
  const float* sm = smol + (size_t)bh * 4096;
  #pragma unroll
  for (int fm = 0; fm < 2; fm++)
    #pragma unroll
    for (int fn = 0; fn < 2; fn++)
      #pragma unroll
      for (int j = 0; j < 4; j++){
        int q  = wm * 32 + fm * 16 + (lane >> 4) * 4 + j;
        int kp = wn * 32 + fn * 16 + (lane & 15);
        Ss[q * 68 + kp] = sacc[fm][fn][j] * 0.125f + sm[q * 64 + kp];
      }
  __syncthreads();

  {
    int row = w * 16 + (lane >> 2);
    int sub = lane & 3;
    float* srow = &Ss[row * 68];
    float vals[16];
    float mx = -3.4e38f;
    #pragma unroll
    for (int i = 0; i < 16; i++){ vals[i] = srow[sub * 16 + i]; mx = fmaxf(mx, vals[i]); }
    mx = fmaxf(mx, __shfl_xor(mx, 1));
    mx = fmaxf(mx, __shfl_xor(mx, 2));
    float s = 0.f;
    #pragma unroll
    for (int i = 0; i < 16; i++){ vals[i] = __expf(vals[i] - mx); s += vals[i]; }
    s += __shfl_xor(s, 1);
    s += __shfl_xor(s, 2);
    float rinv = 1.f / s;
    short8 o0, o1;
    #pragma unroll
    for (int i = 0; i < 8; i++){ o0[i] = (short)f2b(vals[i] * rinv); o1[i] = (short)f2b(vals[8 + i] * rinv); }
    int c0 = sub * 2, c1 = sub * 2 + 1;
    *(short8*)&ps[row * 64 + (c0 ^ (row & 7)) * 8] = o0;
    *(short8*)&ps[row * 64 + (c1 ^ (row & 7)) * 8] = o1;
  }
  __syncthreads();

  f32x4 oacc[2][2] = {};
  #pragma unroll
  for (int ksi = 0; ksi < 2; ksi++){
    short8 af[2], bfr[2];
    #pragma unroll
    for (int f = 0; f < 2; f++){
      int ra = wm * 32 + f * 16 + (lane & 15);
      int ca = ksi * 4 + (lane >> 4);
      af[f]  = *(const short8*)&ps [ra * 64 + (ca ^ (ra & 7)) * 8];
      int rb = wn * 32 + f * 16 + (lane & 15);
      bfr[f] = *(const short8*)&vts[rb * 64 + (ca ^ (rb & 7)) * 8];
    }
    #pragma unroll
    for (int fm = 0; fm < 2; fm++)
      #pragma unroll
      for (int fn = 0; fn < 2; fn++)
        oacc[fm][fn] = __builtin_amdgcn_mfma_f32_16x16x32_bf16(af[fm], bfr[fn], oacc[fm][fn], 0, 0, 0);
  }
  #pragma unroll
  for (int fm = 0; fm < 2; fm++)
    #pragma unroll
    for (int fn = 0; fn < 2; fn++)
      #pragma unroll
      for (int j = 0; j < 4; j++){
        int q  = wm * 32 + fm * 16 + (lane >> 4) * 4 + j;
        int hd = wn * 32 + fn * 16 + (lane & 15);
        aout[(size_t)(b * 64 + q) * 1024 + h * 64 + hd] = f2b(oacc[fm][fn][j]);
      }
}

// ---------------------------------------------------------------- launcher
extern "C" void kernel_launch(void* const* d_in, const int* in_sizes, int n_in,
                              void* d_out, int out_size, void* d_ws, size_t ws_size,
                              hipStream_t stream){
  const float* x     = (const float*)d_in[0];
  const float* wq    = (const float*)d_in[1];
  const float* bq    = (const float*)d_in[2];
  const float* wk    = (const float*)d_in[3];
  const float* bk    = (const float*)d_in[4];
  const float* wv    = (const float*)d_in[5];
  const float* bv    = (const float*)d_in[6];
  const float* wo    = (const float*)d_in[7];
  const float* bo    = (const float*)d_in[8];
  const float* sc_w  = (const float*)d_in[9];
  const float* sh1_w = (const float*)d_in[10];
  const float* sh1_b = (const float*)d_in[11];
  const float* ln1_g = (const float*)d_in[12];
  const float* ln1_b = (const float*)d_in[13];
  const float* sg_w  = (const float*)d_in[14];
  const float* sg_b  = (const float*)d_in[15];
  const float* ln2_g = (const float*)d_in[16];
  const float* ln2_b = (const float*)d_in[17];
  const float* swg_w = (const float*)d_in[18];

  char* ws = (char*)d_ws;
  size_t off = 0;
  auto alloc = [&](size_t bytes){ void* p = ws + off; off += (bytes + 255) & ~(size_t)255; return p; };
  u16*   xb    = (u16*)  alloc((size_t)MROWS * EMB * 2);
  u16*   wqkvT = (u16*)  alloc((size_t)NQKV * EMB * 2);
  float* qbias = (float*)alloc((size_t)NQKV * 4);
  u16*   woT   = (u16*)  alloc((size_t)1024 * 1024 * 2);
  u16*   swgT  = (u16*)  alloc((size_t)4096 * 256 * 2);
  u16*   qkvb  = (u16*)  alloc((size_t)MROWS * NQKV * 2);
  float* hid   = (float*)alloc((size_t)512 * 256 * 4);
  u16*   genb  = (u16*)  alloc((size_t)512 * 4096 * 2);
  float* smol  = (float*)alloc((size_t)8192 * 4096 * 4);
  u16*   aout  = (u16*)  alloc((size_t)MROWS * 1024 * 2);

  // --- single fused prep: x->bf16, all weight transposes, pad, bias ---
  prep_all<<<PREP_BLOCKS, 256, 0, stream>>>(x, xb, wq, wk, wv, sc_w, wo, swg_w,
                                            wqkvT, woT, swgT, bq, bk, bv, qbias);

  // --- fused QKV + compressed projection: [32768,1024] @ [1024,3328] ---
  gemm256<1, 1><<<(MROWS / 256) * (NQKV / 256), 512, 0, stream>>>(
      xb, wqkvT, qbias, qkvb, MROWS, NQKV, 1024);

  // --- smolgen chain ---
  smol_hidden<<<BATCH / 2, 512, 0, stream>>>(qkvb, sh1_w, sh1_b, ln1_g, ln1_b, hid);
  smol_gen   <<<BATCH / 2, 512, 0, stream>>>(hid, sg_w, sg_b, ln2_g, ln2_b, genb);
  gemm256<0, 0><<<(8192 / 256) * (4096 / 256), 512, 0, stream>>>(
      genb, swgT, nullptr, smol, 8192, 4096, 256);

  // --- attention ---
  attn_fused<<<BATCH * NH, 256, 0, stream>>>(qkvb, smol, aout);

  // --- output projection: [32768,1024] @ [1024,1024] + bo -> fp32 d_out ---
  gemm256<0, 1><<<(MROWS / 256) * (1024 / 256), 512, 0, stream>>>(
      aout, woT, bo, d_out, MROWS, 1024, 1024);
}

// Round 10
// 782.524 us; speedup vs baseline: 1.2583x; 1.0317x over previous
//
#include <hip/hip_runtime.h>
#include <hip/hip_bf16.h>

typedef unsigned short u16;
typedef __attribute__((ext_vector_type(8))) short short8;
typedef __attribute__((ext_vector_type(4))) float f32x4;
typedef const __attribute__((address_space(1))) void GV;
typedef __attribute__((address_space(3))) void LV;
#define GLOAD16(g, l) __builtin_amdgcn_global_load_lds((GV*)(g), (LV*)(l), 16, 0, 0)
#define BAR() asm volatile("s_barrier" ::: "memory")

#define BATCH 512
#define LSEQ  64
#define EMB   1024
#define NH    16
#define NQKV  3328              // 1024 q | 1024 k | 1024 v | 32 sc | 224 pad (multiple of 256)
#define MROWS (BATCH*LSEQ)      // 32768

__device__ __forceinline__ u16 f2b(float f){
  __hip_bfloat16 h = __float2bfloat16(f);
  return *reinterpret_cast<u16*>(&h);
}
__device__ __forceinline__ float b2f(u16 u){
  return __uint_as_float(((unsigned)u) << 16);
}
__device__ __forceinline__ uint2 pack4(float4 v){
  unsigned lo = (unsigned)f2b(v.x) | ((unsigned)f2b(v.y) << 16);
  unsigned hi = (unsigned)f2b(v.z) | ((unsigned)f2b(v.w) << 16);
  return make_uint2(lo, hi);
}

// ---------------------------------------------------------------- fused prep
// One kernel, block-range sections (confirmed −94us vs 9 launches, R5)
__device__ __forceinline__ void tpose(const float* __restrict__ src, u16* __restrict__ dst,
                                      int K, int N, int dstLd, int dstRowOff,
                                      int blk, int tid, float (*t)[33]){
  int nbx = N >> 5;
  int bx = blk % nbx, by = blk / nbx;
  int n0 = bx << 5, k0 = by << 5;
  int lx = tid & 31, ly = tid >> 5;   // 32 x 8
  #pragma unroll
  for (int i = 0; i < 32; i += 8)
    t[ly + i][lx] = src[(size_t)(k0 + ly + i) * N + n0 + lx];
  __syncthreads();
  #pragma unroll
  for (int i = 0; i < 32; i += 8)
    dst[(size_t)(dstRowOff + n0 + ly + i) * dstLd + k0 + lx] = f2b(t[lx][ly + i]);
}

#define PREP_BLOCKS 38157
__global__ __launch_bounds__(256) void prep_all(const float* __restrict__ x, u16* __restrict__ xb,
                                                const float* __restrict__ wq, const float* __restrict__ wk,
                                                const float* __restrict__ wv, const float* __restrict__ sc_w,
                                                const float* __restrict__ wo, const float* __restrict__ swg_w,
                                                u16* __restrict__ wqkvT, u16* __restrict__ woT,
                                                u16* __restrict__ swgT,
                                                const float* __restrict__ bq, const float* __restrict__ bk,
                                                const float* __restrict__ bv, float* __restrict__ qbias){
  __shared__ float t[32][33];
  const int blk = blockIdx.x, tid = threadIdx.x;
  if (blk < 32768){
    size_t i = ((size_t)blk * 256 + tid) * 4;
    float4 v = *(const float4*)&x[i];
    *(uint2*)&xb[i] = pack4(v);
  } else if (blk < 33792){
    tpose(wq,   wqkvT, 1024, 1024, 1024, 0,    blk - 32768, tid, t);
  } else if (blk < 34816){
    tpose(wk,   wqkvT, 1024, 1024, 1024, 1024, blk - 33792, tid, t);
  } else if (blk < 35840){
    tpose(wv,   wqkvT, 1024, 1024, 1024, 2048, blk - 34816, tid, t);
  } else if (blk < 35872){
    tpose(sc_w, wqkvT, 1024, 32,   1024, 3072, blk - 35840, tid, t);
  } else if (blk < 36896){
    tpose(wo,   woT,   1024, 1024, 1024, 0,    blk - 35872, tid, t);
  } else if (blk < 37920){
    tpose(swg_w, swgT, 256,  4096, 256,  0,    blk - 36896, tid, t);
  } else if (blk < 38144){
    size_t i = (size_t)(blk - 37920) * 1024 + tid * 4;
    *(uint2*)&wqkvT[(size_t)3104 * 1024 + i] = make_uint2(0, 0);
  } else {
    int i = (blk - 38144) * 256 + tid;
    if (i < NQKV){
      float v = 0.f;
      if (i < 1024) v = bq[i];
      else if (i < 2048) v = bk[i - 1024];
      else if (i < 3072) v = bv[i - 2048];
      qbias[i] = v;
    }
  }
}

// ---------------------------------------------------------------- 256x256 8-phase GEMM
// (R2/R5-known-good schedule: QKV 268us, MfmaUtil 36%, 0 bank conflicts — DO NOT
// touch the phase structure; two balancing experiments (R3 a2-prefetch, etc.)
// both regressed.)
template<int OUT_BF16, int HAS_BIAS>
__global__ __launch_bounds__(512, 2) void gemm256(const u16* __restrict__ A,
                                                  const u16* __restrict__ Bt,
                                                  const float* __restrict__ bias,
                                                  void* __restrict__ Cv,
                                                  int M, int N, int K){
  __shared__ u16 lA[2][16384];   // [buf][half*8192 + row*64 + swz_slot*8]
  __shared__ u16 lB[2][16384];
  const int ntn = N >> 8;
  const int nwg = gridDim.x, bid = blockIdx.x;
  const int qq = nwg >> 3, r8 = nwg & 7, xcd = bid & 7, kk = bid >> 3;
  const int wg = (xcd < r8 ? xcd * (qq + 1) : r8 * (qq + 1) + (xcd - r8) * qq) + kk;
  const int tm = wg / ntn, tn = wg % ntn;
  const int m0 = tm << 8, n0 = tn << 8;
  const int tid = threadIdx.x;
  const int w = tid >> 6, lane = tid & 63;
  const int wm = w >> 2, wn = w & 3;
  const int l15 = lane & 15, l4 = lane >> 4;

  size_t ga[2][2], gb[2][2];
  #pragma unroll
  for (int j = 0; j < 2; j++){
    int ci = w * 128 + j * 64 + lane;
    int rh = ci >> 3, s = ci & 7;
    int gk = (s ^ (rh & 7)) * 8;
    #pragma unroll
    for (int h = 0; h < 2; h++){
      ga[h][j] = (size_t)(m0 + h * 128 + rh) * K + gk;
      gb[h][j] = (size_t)(n0 + h * 128 + rh) * K + gk;
    }
  }
  const int nk = K >> 6;

  auto stA = [&](int buf, int h, int kt){
    #pragma unroll
    for (int j = 0; j < 2; j++)
      GLOAD16(A + ga[h][j] + (size_t)kt * 64, &lA[buf][h * 8192 + (w * 128 + j * 64) * 8]);
  };
  auto stB = [&](int buf, int h, int kt){
    #pragma unroll
    for (int j = 0; j < 2; j++)
      GLOAD16(Bt + gb[h][j] + (size_t)kt * 64, &lB[buf][h * 8192 + (w * 128 + j * 64) * 8]);
  };

  // prologue: tile0 {A0,B0,B1,A1}, tile1 {A0,B0,B1}; vmcnt(6) confirms tile0.
  stA(0, 0, 0); stB(0, 0, 0); stB(0, 1, 0); stA(0, 1, 0);
  stA(1, 0, 1); stB(1, 0, 1); stB(1, 1, 1);
  asm volatile("s_waitcnt vmcnt(6)" ::: "memory");
  BAR();

  f32x4 acc[8][4] = {};
  short8 a[4][2], b[4][2];

  for (int t = 0; t < nk; ++t){
    const int cur = t & 1;
    const u16* la = lA[cur];
    const u16* lb = lB[cur];

    // ---- phase 1: ds A0(8) + B0(4); stage A1(t+1); MFMA A0xB0
    #pragma unroll
    for (int f = 0; f < 4; f++){
      int r = f * 32 + wm * 16 + l15;
      #pragma unroll
      for (int ks = 0; ks < 2; ks++){
        int c = ks * 4 + l4;
        a[f][ks] = *(const short8*)&la[r * 64 + ((c ^ (r & 7)) * 8)];
      }
    }
    #pragma unroll
    for (int g = 0; g < 2; g++){
      int r = g * 64 + wn * 16 + l15;
      #pragma unroll
      for (int ks = 0; ks < 2; ks++){
        int c = ks * 4 + l4;
        b[g][ks] = *(const short8*)&lb[r * 64 + ((c ^ (r & 7)) * 8)];
      }
    }
    if (t + 1 < nk) stA(cur ^ 1, 1, t + 1);
    BAR();
    __builtin_amdgcn_s_setprio(1);
    #pragma unroll
    for (int f = 0; f < 4; f++)
      #pragma unroll
      for (int g = 0; g < 2; g++)
        #pragma unroll
        for (int ks = 0; ks < 2; ks++)
          acc[f][g] = __builtin_amdgcn_mfma_f32_16x16x32_bf16(a[f][ks], b[g][ks], acc[f][g], 0, 0, 0);
    __builtin_amdgcn_s_setprio(0);
    BAR();

    // ---- phase 2: ds B1(4); stage A0(t+2); MFMA A0xB1
    #pragma unroll
    for (int g = 2; g < 4; g++){
      int r = (g - 2) * 64 + wn * 16 + l15;
      #pragma unroll
      for (int ks = 0; ks < 2; ks++){
        int c = ks * 4 + l4;
        b[g][ks] = *(const short8*)&lb[8192 + r * 64 + ((c ^ (r & 7)) * 8)];
      }
    }
    if (t + 2 < nk) stA(cur, 0, t + 2);
    BAR();
    __builtin_amdgcn_s_setprio(1);
    #pragma unroll
    for (int f = 0; f < 4; f++)
      #pragma unroll
      for (int g = 2; g < 4; g++)
        #pragma unroll
        for (int ks = 0; ks < 2; ks++)
          acc[f][g] = __builtin_amdgcn_mfma_f32_16x16x32_bf16(a[f][ks], b[g][ks], acc[f][g], 0, 0, 0);
    __builtin_amdgcn_s_setprio(0);
    BAR();

    // ---- phase 3: ds A1(8); stage B0(t+2); MFMA A1xB1
    #pragma unroll
    for (int f = 0; f < 4; f++){
      int r = f * 32 + wm * 16 + l15;   // rows 128..255 live at lA[...][8192+]
      #pragma unroll
      for (int ks = 0; ks < 2; ks++){
        int c = ks * 4 + l4;
        a[f][ks] = *(const short8*)&la[8192 + r * 64 + ((c ^ (r & 7)) * 8)];
      }
    }
    if (t + 2 < nk) stB(cur, 0, t + 2);
    BAR();
    __builtin_amdgcn_s_setprio(1);
    #pragma unroll
    for (int f = 0; f < 4; f++)
      #pragma unroll
      for (int g = 2; g < 4; g++)
        #pragma unroll
        for (int ks = 0; ks < 2; ks++)
          acc[f + 4][g] = __builtin_amdgcn_mfma_f32_16x16x32_bf16(a[f][ks], b[g][ks], acc[f + 4][g], 0, 0, 0);
    __builtin_amdgcn_s_setprio(0);
    BAR();

    // ---- phase 4: stage B1(t+2); boundary vmcnt; MFMA A1xB0
    if (t + 2 < nk) stB(cur, 1, t + 2);
    if (t + 1 < nk){
      if (t + 2 < nk) asm volatile("s_waitcnt vmcnt(6)" ::: "memory");
      else            asm volatile("s_waitcnt vmcnt(0)" ::: "memory");
    }
    BAR();
    __builtin_amdgcn_s_setprio(1);
    #pragma unroll
    for (int f = 0; f < 4; f++)
      #pragma unroll
      for (int g = 0; g < 2; g++)
        #pragma unroll
        for (int ks = 0; ks < 2; ks++)
          acc[f + 4][g] = __builtin_amdgcn_mfma_f32_16x16x32_bf16(a[f][ks], b[g][ks], acc[f + 4][g], 0, 0, 0);
    __builtin_amdgcn_s_setprio(0);
    BAR();
  }

  // epilogue
  #pragma unroll
  for (int f = 0; f < 8; f++){
    #pragma unroll
    for (int g = 0; g < 4; g++){
      int col = n0 + g * 64 + wn * 16 + l15;
      float bv = HAS_BIAS ? bias[col] : 0.0f;
      #pragma unroll
      for (int j = 0; j < 4; j++){
        int row = m0 + f * 32 + wm * 16 + l4 * 4 + j;
        float v = acc[f][g][j] + bv;
        if (OUT_BF16) ((u16*)Cv)[(size_t)row * N + col] = f2b(v);
        else          ((float*)Cv)[(size_t)row * N + col] = v;
      }
    }
  }
}

// ---------------------------------------------------------------- smolgen hidden
__global__ __launch_bounds__(512) void smol_hidden(const u16* __restrict__ qkvb,
                                                   const float* __restrict__ sh1_w,
                                                   const float* __restrict__ sh1_b,
                                                   const float* __restrict__ ln1_g,
                                                   const float* __restrict__ ln1_b,
                                                   float* __restrict__ hidden){
  const int b0 = blockIdx.x * 2;
  const int tid = threadIdx.x;
  __shared__ u16 cb[2][2048];
  __shared__ float part[8][2][256];
  __shared__ float rs[16];
  {
    int bi = tid >> 8, rem = tid & 255;
    int l = rem >> 2, cc = rem & 3;
    *(short8*)&cb[bi][rem * 8] =
        *(const short8*)&qkvb[(size_t)((b0 + bi) * 64 + l) * NQKV + 3072 + cc * 8];
  }
  __syncthreads();
  const int g = tid >> 6;          // k-group: k in [g*256, g*256+256)
  const int c4 = (tid & 63) * 4;   // cols c4..c4+3
  float4 a0 = {0,0,0,0}, a1 = {0,0,0,0};
  for (int kk2 = 0; kk2 < 256; kk2++){
    int k = g * 256 + kk2;
    float4 wv = *(const float4*)&sh1_w[(size_t)k * 256 + c4];
    float x0 = b2f(cb[0][k]), x1 = b2f(cb[1][k]);
    a0.x += x0 * wv.x; a0.y += x0 * wv.y; a0.z += x0 * wv.z; a0.w += x0 * wv.w;
    a1.x += x1 * wv.x; a1.y += x1 * wv.y; a1.z += x1 * wv.z; a1.w += x1 * wv.w;
  }
  *(float4*)&part[g][0][c4] = a0;
  *(float4*)&part[g][1][c4] = a1;
  __syncthreads();
  const int bi = tid >> 8, col = tid & 255;
  float y = sh1_b[col];
  #pragma unroll
  for (int g2 = 0; g2 < 8; g2++) y += part[g2][bi][col];
  y = y / (1.f + __expf(-y));
  float s = y, q = y * y;
  #pragma unroll
  for (int o = 32; o > 0; o >>= 1){ s += __shfl_down(s, o); q += __shfl_down(q, o); }
  int wv_ = tid >> 6;
  if ((tid & 63) == 0){ rs[wv_ * 2] = s; rs[wv_ * 2 + 1] = q; }
  __syncthreads();
  float S = 0, Q = 0;
  #pragma unroll
  for (int w2 = 0; w2 < 4; w2++){ S += rs[(bi * 4 + w2) * 2]; Q += rs[(bi * 4 + w2) * 2 + 1]; }
  float m = S * (1.f / 256.f), var = Q * (1.f / 256.f) - m * m;
  hidden[(size_t)(b0 + bi) * 256 + col] =
      (y - m) * rsqrtf(var + 1e-3f) * ln1_g[col] + ln1_b[col];
}

// ---------------------------------------------------------------- smolgen gen
__global__ __launch_bounds__(512) void smol_gen(const float* __restrict__ hidden,
                                                const float* __restrict__ sg_w,
                                                const float* __restrict__ sg_b,
                                                const float* __restrict__ ln2_g,
                                                const float* __restrict__ ln2_b,
                                                u16* __restrict__ genb){
  const int b0 = blockIdx.x * 2;
  const int tid = threadIdx.x;
  __shared__ float hb[2][256];
  __shared__ float rs[32];
  if (tid < 512) hb[tid >> 8][tid & 255] = hidden[(size_t)(b0 + (tid >> 8)) * 256 + (tid & 255)];
  __syncthreads();
  const int c4 = tid * 4;   // chunk0 col, chunk1 col = 2048 + c4
  float4 A00 = {0,0,0,0}, A01 = {0,0,0,0}, A10 = {0,0,0,0}, A11 = {0,0,0,0};
  for (int k = 0; k < 256; k++){
    float h0 = hb[0][k], h1 = hb[1][k];
    float4 w0 = *(const float4*)&sg_w[(size_t)k * 4096 + c4];
    float4 w1 = *(const float4*)&sg_w[(size_t)k * 4096 + 2048 + c4];
    A00.x += h0 * w0.x; A00.y += h0 * w0.y; A00.z += h0 * w0.z; A00.w += h0 * w0.w;
    A01.x += h0 * w1.x; A01.y += h0 * w1.y; A01.z += h0 * w1.z; A01.w += h0 * w1.w;
    A10.x += h1 * w0.x; A10.y += h1 * w0.y; A10.z += h1 * w0.z; A10.w += h1 * w0.w;
    A11.x += h1 * w1.x; A11.y += h1 * w1.y; A11.z += h1 * w1.z; A11.w += h1 * w1.w;
  }
  float4 b0v = *(const float4*)&sg_b[c4];
  float4 b1v = *(const float4*)&sg_b[2048 + c4];
  float s0 = 0, q0 = 0, s1 = 0, q1 = 0;
  float* p;
  #pragma unroll
  for (int e = 0; e < 4; e++){
    p = (float*)&A00; float y = p[e] + ((float*)&b0v)[e]; y = y / (1.f + __expf(-y)); p[e] = y; s0 += y; q0 += y * y;
    p = (float*)&A01; y = p[e] + ((float*)&b1v)[e]; y = y / (1.f + __expf(-y)); p[e] = y; s0 += y; q0 += y * y;
    p = (float*)&A10; y = p[e] + ((float*)&b0v)[e]; y = y / (1.f + __expf(-y)); p[e] = y; s1 += y; q1 += y * y;
    p = (float*)&A11; y = p[e] + ((float*)&b1v)[e]; y = y / (1.f + __expf(-y)); p[e] = y; s1 += y; q1 += y * y;
  }
  #pragma unroll
  for (int o = 32; o > 0; o >>= 1){
    s0 += __shfl_down(s0, o); q0 += __shfl_down(q0, o);
    s1 += __shfl_down(s1, o); q1 += __shfl_down(q1, o);
  }
  int wv_ = tid >> 6;
  if ((tid & 63) == 0){ rs[wv_ * 4] = s0; rs[wv_ * 4 + 1] = q0; rs[wv_ * 4 + 2] = s1; rs[wv_ * 4 + 3] = q1; }
  __syncthreads();
  float S0 = 0, Q0 = 0, S1 = 0, Q1 = 0;
  #pragma unroll
  for (int w2 = 0; w2 < 8; w2++){
    S0 += rs[w2 * 4]; Q0 += rs[w2 * 4 + 1]; S1 += rs[w2 * 4 + 2]; Q1 += rs[w2 * 4 + 3];
  }
  float m0 = S0 * (1.f / 4096.f), v0 = Q0 * (1.f / 4096.f) - m0 * m0;
  float m1 = S1 * (1.f / 4096.f), v1 = Q1 * (1.f / 4096.f) - m1 * m1;
  float is0 = rsqrtf(v0 + 1e-3f), is1 = rsqrtf(v1 + 1e-3f);
  float4 g0 = *(const float4*)&ln2_g[c4],        gb0 = *(const float4*)&ln2_b[c4];
  float4 g1 = *(const float4*)&ln2_g[2048 + c4], gb1 = *(const float4*)&ln2_b[2048 + c4];
  float4 o00, o01, o10, o11;
  #pragma unroll
  for (int e = 0; e < 4; e++){
    ((float*)&o00)[e] = (((float*)&A00)[e] - m0) * is0 * ((float*)&g0)[e] + ((float*)&gb0)[e];
    ((float*)&o01)[e] = (((float*)&A01)[e] - m0) * is0 * ((float*)&g1)[e] + ((float*)&gb1)[e];
    ((float*)&o10)[e] = (((float*)&A10)[e] - m1) * is1 * ((float*)&g0)[e] + ((float*)&gb0)[e];
    ((float*)&o11)[e] = (((float*)&A11)[e] - m1) * is1 * ((float*)&g1)[e] + ((float*)&gb1)[e];
  }
  *(uint2*)&genb[(size_t)(b0    ) * 4096 + c4]        = pack4(o00);
  *(uint2*)&genb[(size_t)(b0    ) * 4096 + 2048 + c4] = pack4(o01);
  *(uint2*)&genb[(size_t)(b0 + 1) * 4096 + c4]        = pack4(o10);
  *(uint2*)&genb[(size_t)(b0 + 1) * 4096 + 2048 + c4] = pack4(o11);
}

// ---------------------------------------------------------------- fused attention
// Wave-complete rows: each of 4 waves computes a 16x64 S strip (sacc[4]), so
// softmax is fully in-register (16-lane-group shfl_xor) — no Ss LDS roundtrip.
// LDS 49.4 -> 32 KB (3 -> 5 blocks/CU). smol read is bf16.
__global__ __launch_bounds__(256) void attn_fused(const u16* __restrict__ qkvb,
                                                  const u16* __restrict__ smolb,
                                                  u16* __restrict__ aout){
  const int bh = blockIdx.x;
  const int b = bh >> 4, h = bh & 15;
  __shared__ u16 qs[4096], kts[4096], vts[4096], ps[4096];
  const int tid = threadIdx.x, w = tid >> 6, lane = tid & 63;
  const int l15 = lane & 15, g = lane >> 4;

  const u16* qb = qkvb + (size_t)(b * 64) * NQKV + h * 64;
  const u16* kb = qb + 1024;
  const u16* vb = qb + 2048;

  // stage q,k row-major (chunk XOR-swizzle) and v^T
  #pragma unroll
  for (int i = 0; i < 2; i++){
    int c = i * 256 + tid;
    int r = c >> 3, cc = c & 7;
    int pc = cc ^ (r & 7);
    *(short8*)&qs [r * 64 + pc * 8] = *(const short8*)&qb[(size_t)r * NQKV + cc * 8];
    *(short8*)&kts[r * 64 + pc * 8] = *(const short8*)&kb[(size_t)r * NQKV + cc * 8];
    short8 vv = *(const short8*)&vb[(size_t)r * NQKV + cc * 8];
    #pragma unroll
    for (int j = 0; j < 8; j++){
      int hd = cc * 8 + j;
      int pcv = (r >> 3) ^ (hd & 7);
      vts[hd * 64 + pcv * 8 + (r & 7)] = (u16)vv[j];
    }
  }
  __syncthreads();

  // QK^T: wave w -> rows w*16..w*16+15, all 64 cols (4 fn frags)
  f32x4 sacc[4] = {};
  #pragma unroll
  for (int ksi = 0; ksi < 2; ksi++){
    int ra = w * 16 + l15;
    int ca = ksi * 4 + g;
    short8 af = *(const short8*)&qs[ra * 64 + ((ca ^ (ra & 7)) * 8)];
    #pragma unroll
    for (int fn = 0; fn < 4; fn++){
      int rb = fn * 16 + l15;
      short8 bf = *(const short8*)&kts[rb * 64 + ((ca ^ (rb & 7)) * 8)];
      sacc[fn] = __builtin_amdgcn_mfma_f32_16x16x32_bf16(af, bf, sacc[fn], 0, 0, 0);
    }
  }

  // in-register softmax over rows q = w*16 + g*4 + j
  const u16* sm = smolb + (size_t)bh * 4096;
  float vals[4][4];     // [fn][j]
  float mx[4] = {-3.4e38f, -3.4e38f, -3.4e38f, -3.4e38f};
  #pragma unroll
  for (int fn = 0; fn < 4; fn++)
    #pragma unroll
    for (int j = 0; j < 4; j++){
      int q = w * 16 + g * 4 + j;
      float v = sacc[fn][j] * 0.125f + b2f(sm[q * 64 + fn * 16 + l15]);
      vals[fn][j] = v;
      mx[j] = fmaxf(mx[j], v);
    }
  #pragma unroll
  for (int o = 1; o < 16; o <<= 1)
    #pragma unroll
    for (int j = 0; j < 4; j++) mx[j] = fmaxf(mx[j], __shfl_xor(mx[j], o));
  float sum[4] = {0, 0, 0, 0};
  #pragma unroll
  for (int fn = 0; fn < 4; fn++)
    #pragma unroll
    for (int j = 0; j < 4; j++){
      vals[fn][j] = __expf(vals[fn][j] - mx[j]);
      sum[j] += vals[fn][j];
    }
  #pragma unroll
  for (int o = 1; o < 16; o <<= 1)
    #pragma unroll
    for (int j = 0; j < 4; j++) sum[j] += __shfl_xor(sum[j], o);
  float rinv[4];
  #pragma unroll
  for (int j = 0; j < 4; j++) rinv[j] = 1.f / sum[j];

  // write P (bf16) to ps, chunk-swizzled row-major
  #pragma unroll
  for (int fn = 0; fn < 4; fn++)
    #pragma unroll
    for (int j = 0; j < 4; j++){
      int q = w * 16 + g * 4 + j;
      int c = fn * 16 + l15;
      int cs = (c & 7) | ((((c >> 3) ^ (q & 7)) & 7) << 3);
      ps[q * 64 + cs] = f2b(vals[fn][j] * rinv[j]);
    }
  __syncthreads();

  // O = P @ V : wave w -> rows w*16..+15, all 64 hd
  f32x4 oacc[4] = {};
  #pragma unroll
  for (int ksi = 0; ksi < 2; ksi++){
    int ra = w * 16 + l15;
    int ca = ksi * 4 + g;
    short8 af = *(const short8*)&ps[ra * 64 + ((ca ^ (ra & 7)) * 8)];
    #pragma unroll
    for (int fn = 0; fn < 4; fn++){
      int rb = fn * 16 + l15;
      short8 bf = *(const short8*)&vts[rb * 64 + ((ca ^ (rb & 7)) * 8)];
      oacc[fn] = __builtin_amdgcn_mfma_f32_16x16x32_bf16(af, bf, oacc[fn], 0, 0, 0);
    }
  }
  #pragma unroll
  for (int fn = 0; fn < 4; fn++)
    #pragma unroll
    for (int j = 0; j < 4; j++){
      int q  = w * 16 + g * 4 + j;
      int hd = fn * 16 + l15;
      aout[(size_t)(b * 64 + q) * 1024 + h * 64 + hd] = f2b(oacc[fn][j]);
    }
}

// ---------------------------------------------------------------- launcher
extern "C" void kernel_launch(void* const* d_in, const int* in_sizes, int n_in,
                              void* d_out, int out_size, void* d_ws, size_t ws_size,
                              hipStream_t stream){
  const float* x     = (const float*)d_in[0];
  const float* wq    = (const float*)d_in[1];
  const float* bq    = (const float*)d_in[2];
  const float* wk    = (const float*)d_in[3];
  const float* bk    = (const float*)d_in[4];
  const float* wv    = (const float*)d_in[5];
  const float* bv    = (const float*)d_in[6];
  const float* wo    = (const float*)d_in[7];
  const float* bo    = (const float*)d_in[8];
  const float* sc_w  = (const float*)d_in[9];
  const float* sh1_w = (const float*)d_in[10];
  const float* sh1_b = (const float*)d_in[11];
  const float* ln1_g = (const float*)d_in[12];
  const float* ln1_b = (const float*)d_in[13];
  const float* sg_w  = (const float*)d_in[14];
  const float* sg_b  = (const float*)d_in[15];
  const float* ln2_g = (const float*)d_in[16];
  const float* ln2_b = (const float*)d_in[17];
  const float* swg_w = (const float*)d_in[18];

  char* ws = (char*)d_ws;
  size_t off = 0;
  auto alloc = [&](size_t bytes){ void* p = ws + off; off += (bytes + 255) & ~(size_t)255; return p; };
  u16*   xb    = (u16*)  alloc((size_t)MROWS * EMB * 2);
  u16*   wqkvT = (u16*)  alloc((size_t)NQKV * EMB * 2);
  float* qbias = (float*)alloc((size_t)NQKV * 4);
  u16*   woT   = (u16*)  alloc((size_t)1024 * 1024 * 2);
  u16*   swgT  = (u16*)  alloc((size_t)4096 * 256 * 2);
  u16*   qkvb  = (u16*)  alloc((size_t)MROWS * NQKV * 2);
  float* hid   = (float*)alloc((size_t)512 * 256 * 4);
  u16*   genb  = (u16*)  alloc((size_t)512 * 4096 * 2);
  u16*   smolb = (u16*)  alloc((size_t)8192 * 4096 * 2);   // bf16 logit bias
  u16*   aout  = (u16*)  alloc((size_t)MROWS * 1024 * 2);

  // --- single fused prep: x->bf16, all weight transposes, pad, bias ---
  prep_all<<<PREP_BLOCKS, 256, 0, stream>>>(x, xb, wq, wk, wv, sc_w, wo, swg_w,
                                            wqkvT, woT, swgT, bq, bk, bv, qbias);

  // --- fused QKV + compressed projection: [32768,1024] @ [1024,3328] ---
  gemm256<1, 1><<<(MROWS / 256) * (NQKV / 256), 512, 0, stream>>>(
      xb, wqkvT, qbias, qkvb, MROWS, NQKV, 1024);

  // --- smolgen chain ---
  smol_hidden<<<BATCH / 2, 512, 0, stream>>>(qkvb, sh1_w, sh1_b, ln1_g, ln1_b, hid);
  smol_gen   <<<BATCH / 2, 512, 0, stream>>>(hid, sg_w, sg_b, ln2_g, ln2_b, genb);
  gemm256<1, 0><<<(8192 / 256) * (4096 / 256), 512, 0, stream>>>(
      genb, swgT, nullptr, smolb, 8192, 4096, 256);

  // --- attention ---
  attn_fused<<<BATCH * NH, 256, 0, stream>>>(qkvb, smolb, aout);

  // --- output projection: [32768,1024] @ [1024,1024] + bo -> fp32 d_out ---
  gemm256<0, 1><<<(MROWS / 256) * (1024 / 256), 512, 0, stream>>>(
      aout, woT, bo, d_out, MROWS, 1024, 1024);
}